// Round 11
// baseline (190.504 us; speedup 1.0000x reference)
//
#include <hip/hip_runtime.h>
#include <math.h>

#define NF 128
#define HD 8
#define NPG 2000          // nodes per graph
#define EPB 8000          // edges per sort chunk (4 chunks per graph)
#define LPB 8             // layer blocks per graph
#define LNPB 250          // nodes per layer block
#define SLOPE 0.01f

__device__ __forceinline__ float lrelu(float v) {
    return v > 0.0f ? v : SLOPE * v;
}

// ---------------------------------------------------------------------------
// K1: t1 = x @ W1a  (N x 128)@(128 x 8), coalesced via LDS staging.
// ---------------------------------------------------------------------------
__global__ __launch_bounds__(256) void k_feat(const float* __restrict__ x,
                                              const float* __restrict__ W1a,
                                              float* __restrict__ t1, int N) {
    __shared__ float tile[64 * 132];   // 33 KiB
    __shared__ float wl[NF * HD];      // 4 KiB

    const int t = threadIdx.x;
    const size_t base = (size_t)blockIdx.x * 64;

    ((float4*)wl)[t] = ((const float4*)W1a)[t];

    const float4* xg = (const float4*)(x + base * NF);
#pragma unroll
    for (int i = 0; i < 8; ++i) {
        int f4 = t + i * 256;
        float4 v = xg[f4];
        int flat = f4 * 4;
        int n = flat >> 7;
        int k = flat & 127;
        *(float4*)(tile + n * 132 + k) = v;
    }
    __syncthreads();

    const int n = t >> 2;
    const int c0 = (t & 3) * 2;
    float acc0 = 0.0f, acc1 = 0.0f;
    const float* row = tile + n * 132;
#pragma unroll
    for (int k4 = 0; k4 < 32; ++k4) {
        float4 r = *(const float4*)(row + k4 * 4);
        int kb = k4 * 4 * HD;
        acc0 += r.x * wl[kb + c0];          acc1 += r.x * wl[kb + c0 + 1];
        acc0 += r.y * wl[kb + HD + c0];     acc1 += r.y * wl[kb + HD + c0 + 1];
        acc0 += r.z * wl[kb + 2*HD + c0];   acc1 += r.z * wl[kb + 2*HD + c0 + 1];
        acc0 += r.w * wl[kb + 3*HD + c0];   acc1 += r.w * wl[kb + 3*HD + c0 + 1];
    }
    *(float2*)(t1 + (base + n) * HD + c0) = make_float2(acc0, acc1);
}

// ---------------------------------------------------------------------------
// K2: per-chunk counting sort, fully in LDS. 256 blocks (4 per graph).
// ---------------------------------------------------------------------------
__global__ __launch_bounds__(1024) void k_sort(const int* __restrict__ ei,
                                               int* __restrict__ gcol,
                                               int* __restrict__ rpc,
                                               int E) {
    __shared__ int cnt[NPG];      // counts -> cursors (8 KB)
    __shared__ int srt[EPB];      // sorted srcs (32 KB)
    __shared__ int wtot[16], wpre[16];

    const int b = blockIdx.x;     // chunk id
    const int g = b >> 2;
    const int tid = threadIdx.x;
    const int lane = tid & 63;
    const int wv = tid >> 6;
    const int nodeBase = g * NPG;
    const int e0 = b * EPB;

    for (int i = tid; i < NPG; i += 1024) cnt[i] = 0;
    __syncthreads();

    for (int e = e0 + tid; e < e0 + EPB; e += 1024) {
        int dl = ei[E + e] - nodeBase;
        atomicAdd(&cnt[dl], 1);               // native ds_add_u32
    }
    __syncthreads();

    int c0 = 0, c1 = 0;
    if (tid < 1000) { c0 = cnt[2 * tid]; c1 = cnt[2 * tid + 1]; }
    int s = c0 + c1;
    int isc = s;
#pragma unroll
    for (int d = 1; d < 64; d <<= 1) {
        int o = __shfl_up(isc, d);
        if (lane >= d) isc += o;
    }
    if (lane == 63) wtot[wv] = isc;
    __syncthreads();
    if (wv == 0) {
        int v = (lane < 16) ? wtot[lane] : 0;
        int iv = v;
#pragma unroll
        for (int d = 1; d < 16; d <<= 1) {
            int o = __shfl_up(iv, d);
            if (lane >= d) iv += o;
        }
        if (lane < 16) wpre[lane] = iv - v;
    }
    __syncthreads();
    int excl = isc - s + wpre[wv];

    int* rpb = rpc + (size_t)b * (NPG + 1);
    if (tid < 1000) {
        cnt[2 * tid]     = excl;
        cnt[2 * tid + 1] = excl + c0;
        rpb[2 * tid]     = excl;
        rpb[2 * tid + 1] = excl + c0;
    }
    if (tid == 0) rpb[NPG] = EPB;
    __syncthreads();

    for (int e = e0 + tid; e < e0 + EPB; e += 1024) {
        int src = ei[e] - nodeBase;               // LOCAL src
        int dl = ei[E + e] - nodeBase;
        int pos = atomicAdd(&cnt[dl], 1);         // ds_add_rtn_u32
        srt[pos] = src;
    }
    __syncthreads();

    int4* dst4 = (int4*)(gcol + (size_t)b * EPB);
    const int4* s4 = (const int4*)srt;
    for (int i = tid; i < EPB / 4; i += 1024) dst4[i] = s4[i];
}

// ---------------------------------------------------------------------------
// K3: layer 1. 8 blocks/graph x 1024 thr = 512 blocks, 2 blocks/CU (LDS
// 2x64.5KB < 160KB; launch_bounds(1024,8) caps VGPR at 64) -> 32 waves/CU.
// (node,chunk)-parallel gather: tid = node*4+chunk, ~4-edge chain per thread,
// quad shfl_xor reduce, chunk-0 lane runs MLP1 + u = h@W2a.
// Split LDS tables lo4[n]/hi4[n] keep bank groups uniform.
// ---------------------------------------------------------------------------
__global__ __launch_bounds__(1024, 8) void k_l1(
    const float* __restrict__ t1, const int* __restrict__ rpc,
    const int* __restrict__ gcol, float* __restrict__ u,
    const float* __restrict__ b1a, const float* __restrict__ W1b,
    const float* __restrict__ b1b, const float* __restrict__ W2a)
{
    __shared__ float tbl[NPG * HD];   // 62.5 KiB: lo4[2000] then hi4[2000]
    __shared__ float wts[144];        // b1a[8] W1b[64] b1b[8] W2a[64]

    const int b = blockIdx.x;
    const int g = b >> 3;
    const int q = b & 7;
    const int tid = threadIdx.x;

    if (tid < 144) {
        float v;
        if (tid < 8)       v = b1a[tid];
        else if (tid < 72) v = W1b[tid - 8];
        else if (tid < 80) v = b1b[tid - 72];
        else               v = W2a[tid - 80];
        wts[tid] = v;
    }

    // stage slice: 4000 float4 -> split lo/hi tables
    const float4* src4 = (const float4*)(t1 + (size_t)g * NPG * HD);
    float4* lo4 = (float4*)tbl;
    float4* hi4 = lo4 + NPG;
#pragma unroll
    for (int i = 0; i < 4; ++i) {
        int idx = tid + i * 1024;
        if (idx < 2 * NPG) {
            float4 v = src4[idx];
            int n = idx >> 1;
            if (idx & 1) hi4[n] = v; else lo4[n] = v;
        }
    }
    __syncthreads();

    if (tid < 4 * LNPB) {
        const int node = tid >> 2;            // 0..249
        const int p = tid & 3;                // chunk
        const int nl = q * LNPB + node;
        const int* rpb  = rpc + (size_t)((g << 2) + p) * (NPG + 1);
        const int* colp = gcol + (size_t)((g << 2) + p) * EPB;
        int rs = rpb[nl], re = rpb[nl + 1];
        float a0 = 0, a1 = 0, a2 = 0, a3 = 0, a4 = 0, a5 = 0, a6 = 0, a7 = 0;
        for (int e = rs; e < re; ++e) {
            int sl = colp[e];
            float4 pa = lo4[sl];
            float4 pb = hi4[sl];
            a0 += pa.x; a1 += pa.y; a2 += pa.z; a3 += pa.w;
            a4 += pb.x; a5 += pb.y; a6 += pb.z; a7 += pb.w;
        }
        // reduce across the 4 chunk lanes (quad)
#pragma unroll
        for (int off = 1; off <= 2; off <<= 1) {
            a0 += __shfl_xor(a0, off); a1 += __shfl_xor(a1, off);
            a2 += __shfl_xor(a2, off); a3 += __shfl_xor(a3, off);
            a4 += __shfl_xor(a4, off); a5 += __shfl_xor(a5, off);
            a6 += __shfl_xor(a6, off); a7 += __shfl_xor(a7, off);
        }
        if (p == 0) {
            float4 tA = lo4[nl], tB = hi4[nl];     // self feature
            float z[HD];
            z[0] = lrelu(tA.x + a0 + wts[0]); z[1] = lrelu(tA.y + a1 + wts[1]);
            z[2] = lrelu(tA.z + a2 + wts[2]); z[3] = lrelu(tA.w + a3 + wts[3]);
            z[4] = lrelu(tB.x + a4 + wts[4]); z[5] = lrelu(tB.y + a5 + wts[5]);
            z[6] = lrelu(tB.z + a6 + wts[6]); z[7] = lrelu(tB.w + a7 + wts[7]);

            float h[HD];
#pragma unroll
            for (int j = 0; j < HD; ++j) {
                float acc = wts[72 + j];
#pragma unroll
                for (int c = 0; c < HD; ++c) acc += z[c] * wts[8 + c * HD + j];
                h[j] = lrelu(acc);
            }
            float uu[HD];
#pragma unroll
            for (int j = 0; j < HD; ++j) {
                float acc = 0.0f;
#pragma unroll
                for (int c = 0; c < HD; ++c) acc += h[c] * wts[80 + c * HD + j];
                uu[j] = acc;
            }
            float* ur = u + ((size_t)g * NPG + nl) * HD;
            *(float4*)ur       = make_float4(uu[0], uu[1], uu[2], uu[3]);
            *(float4*)(ur + 4) = make_float4(uu[4], uu[5], uu[6], uu[7]);
        }
    }
}

// ---------------------------------------------------------------------------
// K4: layer 2, same (node,chunk) structure over u; MLP2 + FC1 + FC2 partials;
// plain-store per-block partial (no device-scope sync). k_fin finalizes.
// ---------------------------------------------------------------------------
__global__ __launch_bounds__(1024, 8) void k_l2(
    const float* __restrict__ u, const int* __restrict__ rpc,
    const int* __restrict__ gcol,
    const float* __restrict__ b2a, const float* __restrict__ W2b,
    const float* __restrict__ b2b, const float* __restrict__ Wf1,
    const float* __restrict__ bf1, const float* __restrict__ Wf2,
    float* __restrict__ bparts)
{
    __shared__ float tbl[NPG * HD];   // 62.5 KiB split tables
    __shared__ float wts[89];         // b2a[8] W2b[64] b2b[8] Wf1[8] bf1[1]
    __shared__ float red[32];

    const int b = blockIdx.x;
    const int g = b >> 3;
    const int q = b & 7;
    const int tid = threadIdx.x;
    const int lane = tid & 63;
    const int wv = tid >> 6;

    if (tid < 89) {
        float v;
        if (tid < 8)       v = b2a[tid];
        else if (tid < 72) v = W2b[tid - 8];
        else if (tid < 80) v = b2b[tid - 72];
        else if (tid < 88) v = Wf1[tid - 80];
        else               v = bf1[0];
        wts[tid] = v;
    }

    const float4* src4 = (const float4*)(u + (size_t)g * NPG * HD);
    float4* lo4 = (float4*)tbl;
    float4* hi4 = lo4 + NPG;
#pragma unroll
    for (int i = 0; i < 4; ++i) {
        int idx = tid + i * 1024;
        if (idx < 2 * NPG) {
            float4 v = src4[idx];
            int n = idx >> 1;
            if (idx & 1) hi4[n] = v; else lo4[n] = v;
        }
    }
    __syncthreads();

    float acc0 = 0.0f, acc1 = 0.0f;
    if (tid < 4 * LNPB) {
        const int node = tid >> 2;
        const int p = tid & 3;
        const int nl = q * LNPB + node;
        const int* rpb  = rpc + (size_t)((g << 2) + p) * (NPG + 1);
        const int* colp = gcol + (size_t)((g << 2) + p) * EPB;
        int rs = rpb[nl], re = rpb[nl + 1];
        float a0 = 0, a1 = 0, a2 = 0, a3 = 0, a4 = 0, a5 = 0, a6 = 0, a7 = 0;
        for (int e = rs; e < re; ++e) {
            int sl = colp[e];
            float4 pa = lo4[sl];
            float4 pb = hi4[sl];
            a0 += pa.x; a1 += pa.y; a2 += pa.z; a3 += pa.w;
            a4 += pb.x; a5 += pb.y; a6 += pb.z; a7 += pb.w;
        }
#pragma unroll
        for (int off = 1; off <= 2; off <<= 1) {
            a0 += __shfl_xor(a0, off); a1 += __shfl_xor(a1, off);
            a2 += __shfl_xor(a2, off); a3 += __shfl_xor(a3, off);
            a4 += __shfl_xor(a4, off); a5 += __shfl_xor(a5, off);
            a6 += __shfl_xor(a6, off); a7 += __shfl_xor(a7, off);
        }
        if (p == 0) {
            float4 uA = lo4[nl], uB = hi4[nl];
            float z[HD];
            z[0] = lrelu(uA.x + a0 + wts[0]); z[1] = lrelu(uA.y + a1 + wts[1]);
            z[2] = lrelu(uA.z + a2 + wts[2]); z[3] = lrelu(uA.w + a3 + wts[3]);
            z[4] = lrelu(uB.x + a4 + wts[4]); z[5] = lrelu(uB.y + a5 + wts[5]);
            z[6] = lrelu(uB.z + a6 + wts[6]); z[7] = lrelu(uB.w + a7 + wts[7]);

            float sv = wts[88];
#pragma unroll
            for (int j = 0; j < HD; ++j) {
                float acc = wts[72 + j];
#pragma unroll
                for (int c = 0; c < HD; ++c) acc += z[c] * wts[8 + c * HD + j];
                sv += lrelu(acc) * wts[80 + j];
            }
            float pf = lrelu(sv);
            float2 wf = *(const float2*)(Wf2 + (size_t)nl * 2);
            acc0 = pf * wf.x;
            acc1 = pf * wf.y;
        }
    }

#pragma unroll
    for (int off = 32; off > 0; off >>= 1) {
        acc0 += __shfl_down(acc0, off);
        acc1 += __shfl_down(acc1, off);
    }
    if (lane == 0) { red[wv * 2] = acc0; red[wv * 2 + 1] = acc1; }
    __syncthreads();

    if (tid == 0) {
        float y0 = 0.f, y1 = 0.f;
#pragma unroll
        for (int w = 0; w < 16; ++w) { y0 += red[w * 2]; y1 += red[w * 2 + 1]; }
        *(float2*)(bparts + (size_t)b * 2) = make_float2(y0, y1);
    }
}

// ---------------------------------------------------------------------------
// K5: finalize — one thread per graph sums 8 block partials, log_softmax.
// ---------------------------------------------------------------------------
__global__ __launch_bounds__(64) void k_fin(const float* __restrict__ bparts,
                                            const float* __restrict__ bf2,
                                            float* __restrict__ out, int Bn) {
    int g = threadIdx.x;
    if (g >= Bn) return;
    float y0 = bf2[0], y1 = bf2[1];
#pragma unroll
    for (int b = 0; b < LPB; ++b) {
        float2 v = *(const float2*)(bparts + (size_t)(g * LPB + b) * 2);
        y0 += v.x; y1 += v.y;
    }
    float m = fmaxf(y0, y1);
    float lse = m + logf(expf(y0 - m) + expf(y1 - m));
    out[g * 2 + 0] = y0 - lse;
    out[g * 2 + 1] = y1 - lse;
}

// ---------------------------------------------------------------------------
extern "C" void kernel_launch(void* const* d_in, const int* in_sizes, int n_in,
                              void* d_out, int out_size, void* d_ws, size_t ws_size,
                              hipStream_t stream) {
    const float* x   = (const float*)d_in[0];
    const int*   ei  = (const int*)  d_in[1];
    const float* W1a = (const float*)d_in[3];
    const float* b1a = (const float*)d_in[4];
    const float* W1b = (const float*)d_in[5];
    const float* b1b = (const float*)d_in[6];
    const float* W2a = (const float*)d_in[7];
    const float* b2a = (const float*)d_in[8];
    const float* W2b = (const float*)d_in[9];
    const float* b2b = (const float*)d_in[10];
    const float* Wf1 = (const float*)d_in[11];
    const float* bf1 = (const float*)d_in[12];
    const float* Wf2 = (const float*)d_in[13];
    const float* bf2 = (const float*)d_in[14];

    int N   = in_sizes[0] / NF;        // 128000
    int E   = in_sizes[1] / 2;         // 2048000
    int Bn  = N / NPG;                 // 64 graphs
    int NC  = Bn * 4;                  // 256 chunks

    // workspace carve-up
    float* t1     = (float*)d_ws;                        // N*8        4.1 MB
    float* u      = t1 + (size_t)N * HD;                 // N*8        4.1 MB
    int*   gcol   = (int*)(u + (size_t)N * HD);          // E          8.2 MB
    int*   rpc    = gcol + (size_t)E;                    // NC*(NPG+1) 2.0 MB
    float* bparts = (float*)(rpc + (size_t)NC * (NPG + 1) + 16);  // 512*2

    k_feat <<<N / 64, 256, 0, stream>>>(x, W1a, t1, N);
    k_sort <<<NC, 1024, 0, stream>>>(ei, gcol, rpc, E);
    k_l1   <<<Bn * LPB, 1024, 0, stream>>>(t1, rpc, gcol, u, b1a, W1b, b1b, W2a);
    k_l2   <<<Bn * LPB, 1024, 0, stream>>>(u, rpc, gcol, b2a, W2b, b2b, Wf1,
                                           bf1, Wf2, bparts);
    k_fin  <<<1, 64, 0, stream>>>(bparts, bf2, (float*)d_out, Bn);
}

// Round 12
// 169.309 us; speedup vs baseline: 1.1252x; 1.1252x over previous
//
#include <hip/hip_runtime.h>
#include <math.h>

#define NF 128
#define HD 8
#define NPG 2000          // nodes per graph
#define EPB 8000          // edges per sort chunk (4 chunks per graph)
#define NPB 500           // nodes per layer block (4 blocks/graph)
#define SLOPE 0.01f

__device__ __forceinline__ float lrelu(float v) {
    return v > 0.0f ? v : SLOPE * v;
}

// ---------------------------------------------------------------------------
// K1: fused  [sort blocks 0..255] + [feat blocks 256..2255], 256 thr each.
// Independent inputs/outputs -> run concurrently in one launch; sort first so
// its latency-bound blocks overlap the VALU-bound feat wave-front.
// ---------------------------------------------------------------------------
__global__ __launch_bounds__(256) void k_featsort(
    const float* __restrict__ x, const float* __restrict__ W1a,
    const int* __restrict__ ei, float* __restrict__ t1,
    int* __restrict__ gcol, int* __restrict__ rpc, int N, int E, int NC)
{
    __shared__ union {
        struct { float tile[64 * 132]; float wl[NF * HD]; } f;   // 37.1 KB
        struct { int cnt[NPG]; int srt[EPB]; int wtot[16]; int wpre[16]; } s; // 40.2 KB
    } sm;

    const int t = threadIdx.x;

    if ((int)blockIdx.x < NC) {
        // ---------------- sort chunk b ----------------
        const int b = blockIdx.x;
        const int g = b >> 2;
        const int lane = t & 63;
        const int wv = t >> 6;          // 0..3
        const int nodeBase = g * NPG;
        const int e0 = b * EPB;

        for (int i = t; i < NPG; i += 256) sm.s.cnt[i] = 0;
        __syncthreads();

        for (int e = e0 + t; e < e0 + EPB; e += 256) {
            int dl = ei[E + e] - nodeBase;
            atomicAdd(&sm.s.cnt[dl], 1);          // native ds_add_u32
        }
        __syncthreads();

        // exclusive scan of cnt[0..1999]; thread t<250 owns [8t, 8t+8)
        int lv[8]; int s = 0;
        if (t < 250) {
            int base = t * 8;
#pragma unroll
            for (int j = 0; j < 8; ++j) { lv[j] = sm.s.cnt[base + j]; s += lv[j]; }
        }
        int isc = s;
#pragma unroll
        for (int d = 1; d < 64; d <<= 1) {
            int o = __shfl_up(isc, d);
            if (lane >= d) isc += o;
        }
        if (lane == 63) sm.s.wtot[wv] = isc;
        __syncthreads();
        if (wv == 0) {
            int v = (lane < 4) ? sm.s.wtot[lane] : 0;
            int iv = v;
#pragma unroll
            for (int d = 1; d < 4; d <<= 1) {
                int o = __shfl_up(iv, d);
                if (lane >= d) iv += o;
            }
            if (lane < 4) sm.s.wpre[lane] = iv - v;
        }
        __syncthreads();
        int excl = isc - s + sm.s.wpre[wv];

        int* rpb = rpc + (size_t)b * (NPG + 1);
        if (t < 250) {
            int base = t * 8;
            int run = excl;
#pragma unroll
            for (int j = 0; j < 8; ++j) {
                int idx = base + j;
                rpb[idx] = run;
                sm.s.cnt[idx] = run;
                run += lv[j];
            }
        }
        if (t == 0) rpb[NPG] = EPB;
        __syncthreads();

        // scatter (LOCAL src index)
        for (int e = e0 + t; e < e0 + EPB; e += 256) {
            int src = ei[e] - nodeBase;
            int dl = ei[E + e] - nodeBase;
            int pos = atomicAdd(&sm.s.cnt[dl], 1);   // ds_add_rtn_u32
            sm.s.srt[pos] = src;
        }
        __syncthreads();

        int4* dst4 = (int4*)(gcol + (size_t)b * EPB);
        const int4* s4 = (const int4*)sm.s.srt;
        for (int i = t; i < EPB / 4; i += 256) dst4[i] = s4[i];
    } else {
        // ---------------- feat block ----------------
        const size_t base = (size_t)(blockIdx.x - NC) * 64;

        ((float4*)sm.f.wl)[t] = ((const float4*)W1a)[t];

        const float4* xg = (const float4*)(x + base * NF);
#pragma unroll
        for (int i = 0; i < 8; ++i) {
            int f4 = t + i * 256;
            float4 v = xg[f4];
            int flat = f4 * 4;
            int n = flat >> 7;
            int k = flat & 127;
            *(float4*)(sm.f.tile + n * 132 + k) = v;
        }
        __syncthreads();

        const int n = t >> 2;
        const int c0 = (t & 3) * 2;
        float acc0 = 0.0f, acc1 = 0.0f;
        const float* row = sm.f.tile + n * 132;
#pragma unroll
        for (int k4 = 0; k4 < 32; ++k4) {
            float4 r = *(const float4*)(row + k4 * 4);
            int kb = k4 * 4 * HD;
            acc0 += r.x * sm.f.wl[kb + c0];          acc1 += r.x * sm.f.wl[kb + c0 + 1];
            acc0 += r.y * sm.f.wl[kb + HD + c0];     acc1 += r.y * sm.f.wl[kb + HD + c0 + 1];
            acc0 += r.z * sm.f.wl[kb + 2*HD + c0];   acc1 += r.z * sm.f.wl[kb + 2*HD + c0 + 1];
            acc0 += r.w * sm.f.wl[kb + 3*HD + c0];   acc1 += r.w * sm.f.wl[kb + 3*HD + c0 + 1];
        }
        *(float2*)(t1 + (base + n) * HD + c0) = make_float2(acc0, acc1);
    }
}

// ---------------------------------------------------------------------------
// K2: layer 1 (R10-proven structure). 4 blocks/graph x 512 thr. Stage the
// graph's full t1 slice into LDS as SPLIT tables lo4[n]/hi4[n] (uniform bank
// groups), then 1 node per thread: gather from LDS, MLP1, u = h@W2a.
// NOTE: no min-waves launch bound — forcing VGPR<=64 regressed (R11).
// ---------------------------------------------------------------------------
__global__ __launch_bounds__(512) void k_l1(
    const float* __restrict__ t1, const int* __restrict__ rpc,
    const int* __restrict__ gcol, float* __restrict__ u,
    const float* __restrict__ b1a, const float* __restrict__ W1b,
    const float* __restrict__ b1b, const float* __restrict__ W2a)
{
    __shared__ float tbl[NPG * HD];   // 62.5 KiB: lo4[2000] then hi4[2000]
    __shared__ float wts[144];        // b1a[8] W1b[64] b1b[8] W2a[64]

    const int b = blockIdx.x;
    const int g = b >> 2;
    const int q = b & 3;
    const int tid = threadIdx.x;

    if (tid < 144) {
        float v;
        if (tid < 8)       v = b1a[tid];
        else if (tid < 72) v = W1b[tid - 8];
        else if (tid < 80) v = b1b[tid - 72];
        else               v = W2a[tid - 80];
        wts[tid] = v;
    }

    const float4* src4 = (const float4*)(t1 + (size_t)g * NPG * HD);
    float4* lo4 = (float4*)tbl;
    float4* hi4 = lo4 + NPG;
#pragma unroll
    for (int i = 0; i < 8; ++i) {
        int idx = tid + i * 512;
        if (idx < 2 * NPG) {
            float4 v = src4[idx];
            int n = idx >> 1;
            if (idx & 1) hi4[n] = v; else lo4[n] = v;
        }
    }
    __syncthreads();

    if (tid < NPB) {
        const int nl = q * NPB + tid;
        float a0 = 0, a1 = 0, a2 = 0, a3 = 0, a4 = 0, a5 = 0, a6 = 0, a7 = 0;
#pragma unroll
        for (int p = 0; p < 4; ++p) {
            const int* rpb  = rpc + (size_t)((g << 2) + p) * (NPG + 1);
            const int* colp = gcol + (size_t)((g << 2) + p) * EPB;
            int rs = rpb[nl], re = rpb[nl + 1];
            for (int e = rs; e < re; ++e) {
                int sl = colp[e];
                float4 pa = lo4[sl];
                float4 pb = hi4[sl];
                a0 += pa.x; a1 += pa.y; a2 += pa.z; a3 += pa.w;
                a4 += pb.x; a5 += pb.y; a6 += pb.z; a7 += pb.w;
            }
        }
        float4 tA = lo4[nl], tB = hi4[nl];     // self feature
        float z[HD];
        z[0] = lrelu(tA.x + a0 + wts[0]); z[1] = lrelu(tA.y + a1 + wts[1]);
        z[2] = lrelu(tA.z + a2 + wts[2]); z[3] = lrelu(tA.w + a3 + wts[3]);
        z[4] = lrelu(tB.x + a4 + wts[4]); z[5] = lrelu(tB.y + a5 + wts[5]);
        z[6] = lrelu(tB.z + a6 + wts[6]); z[7] = lrelu(tB.w + a7 + wts[7]);

        float h[HD];
#pragma unroll
        for (int j = 0; j < HD; ++j) {
            float acc = wts[72 + j];
#pragma unroll
            for (int c = 0; c < HD; ++c) acc += z[c] * wts[8 + c * HD + j];
            h[j] = lrelu(acc);
        }
        float uu[HD];
#pragma unroll
        for (int j = 0; j < HD; ++j) {
            float acc = 0.0f;
#pragma unroll
            for (int c = 0; c < HD; ++c) acc += h[c] * wts[80 + c * HD + j];
            uu[j] = acc;
        }
        float* ur = u + ((size_t)g * NPG + nl) * HD;
        *(float4*)ur       = make_float4(uu[0], uu[1], uu[2], uu[3]);
        *(float4*)(ur + 4) = make_float4(uu[4], uu[5], uu[6], uu[7]);
    }
}

// ---------------------------------------------------------------------------
// K3: layer 2 (R10 structure). MLP2 + FC1 + FC2 partials; plain-store
// per-block partial (no device-scope sync — R6 lesson). k_fin finalizes.
// ---------------------------------------------------------------------------
__global__ __launch_bounds__(512) void k_l2(
    const float* __restrict__ u, const int* __restrict__ rpc,
    const int* __restrict__ gcol,
    const float* __restrict__ b2a, const float* __restrict__ W2b,
    const float* __restrict__ b2b, const float* __restrict__ Wf1,
    const float* __restrict__ bf1, const float* __restrict__ Wf2,
    float* __restrict__ bparts)
{
    __shared__ float tbl[NPG * HD];   // 62.5 KiB split tables
    __shared__ float wts[89];         // b2a[8] W2b[64] b2b[8] Wf1[8] bf1[1]
    __shared__ float red[16];

    const int b = blockIdx.x;
    const int g = b >> 2;
    const int q = b & 3;
    const int tid = threadIdx.x;
    const int lane = tid & 63;
    const int wv = tid >> 6;

    if (tid < 89) {
        float v;
        if (tid < 8)       v = b2a[tid];
        else if (tid < 72) v = W2b[tid - 8];
        else if (tid < 80) v = b2b[tid - 72];
        else if (tid < 88) v = Wf1[tid - 80];
        else               v = bf1[0];
        wts[tid] = v;
    }

    const float4* src4 = (const float4*)(u + (size_t)g * NPG * HD);
    float4* lo4 = (float4*)tbl;
    float4* hi4 = lo4 + NPG;
#pragma unroll
    for (int i = 0; i < 8; ++i) {
        int idx = tid + i * 512;
        if (idx < 2 * NPG) {
            float4 v = src4[idx];
            int n = idx >> 1;
            if (idx & 1) hi4[n] = v; else lo4[n] = v;
        }
    }
    __syncthreads();

    float acc0 = 0.0f, acc1 = 0.0f;
    if (tid < NPB) {
        const int nl = q * NPB + tid;
        float a0 = 0, a1 = 0, a2 = 0, a3 = 0, a4 = 0, a5 = 0, a6 = 0, a7 = 0;
#pragma unroll
        for (int p = 0; p < 4; ++p) {
            const int* rpb  = rpc + (size_t)((g << 2) + p) * (NPG + 1);
            const int* colp = gcol + (size_t)((g << 2) + p) * EPB;
            int rs = rpb[nl], re = rpb[nl + 1];
            for (int e = rs; e < re; ++e) {
                int sl = colp[e];
                float4 pa = lo4[sl];
                float4 pb = hi4[sl];
                a0 += pa.x; a1 += pa.y; a2 += pa.z; a3 += pa.w;
                a4 += pb.x; a5 += pb.y; a6 += pb.z; a7 += pb.w;
            }
        }
        float4 uA = lo4[nl], uB = hi4[nl];
        float z[HD];
        z[0] = lrelu(uA.x + a0 + wts[0]); z[1] = lrelu(uA.y + a1 + wts[1]);
        z[2] = lrelu(uA.z + a2 + wts[2]); z[3] = lrelu(uA.w + a3 + wts[3]);
        z[4] = lrelu(uB.x + a4 + wts[4]); z[5] = lrelu(uB.y + a5 + wts[5]);
        z[6] = lrelu(uB.z + a6 + wts[6]); z[7] = lrelu(uB.w + a7 + wts[7]);

        float sv = wts[88];
#pragma unroll
        for (int j = 0; j < HD; ++j) {
            float acc = wts[72 + j];
#pragma unroll
            for (int c = 0; c < HD; ++c) acc += z[c] * wts[8 + c * HD + j];
            sv += lrelu(acc) * wts[80 + j];
        }
        float pf = lrelu(sv);
        float2 wf = *(const float2*)(Wf2 + (size_t)nl * 2);
        acc0 = pf * wf.x;
        acc1 = pf * wf.y;
    }

#pragma unroll
    for (int off = 32; off > 0; off >>= 1) {
        acc0 += __shfl_down(acc0, off);
        acc1 += __shfl_down(acc1, off);
    }
    if (lane == 0) { red[wv * 2] = acc0; red[wv * 2 + 1] = acc1; }
    __syncthreads();

    if (tid == 0) {
        float y0 = 0.f, y1 = 0.f;
#pragma unroll
        for (int w = 0; w < 8; ++w) { y0 += red[w * 2]; y1 += red[w * 2 + 1]; }
        *(float2*)(bparts + (size_t)b * 2) = make_float2(y0, y1);
    }
}

// ---------------------------------------------------------------------------
// K4: finalize — one thread per graph sums 4 block partials, log_softmax.
// ---------------------------------------------------------------------------
__global__ __launch_bounds__(64) void k_fin(const float* __restrict__ bparts,
                                            const float* __restrict__ bf2,
                                            float* __restrict__ out, int Bn) {
    int g = threadIdx.x;
    if (g >= Bn) return;
    float y0 = bf2[0], y1 = bf2[1];
#pragma unroll
    for (int b = 0; b < 4; ++b) {
        float2 v = *(const float2*)(bparts + (size_t)(g * 4 + b) * 2);
        y0 += v.x; y1 += v.y;
    }
    float m = fmaxf(y0, y1);
    float lse = m + logf(expf(y0 - m) + expf(y1 - m));
    out[g * 2 + 0] = y0 - lse;
    out[g * 2 + 1] = y1 - lse;
}

// ---------------------------------------------------------------------------
extern "C" void kernel_launch(void* const* d_in, const int* in_sizes, int n_in,
                              void* d_out, int out_size, void* d_ws, size_t ws_size,
                              hipStream_t stream) {
    const float* x   = (const float*)d_in[0];
    const int*   ei  = (const int*)  d_in[1];
    const float* W1a = (const float*)d_in[3];
    const float* b1a = (const float*)d_in[4];
    const float* W1b = (const float*)d_in[5];
    const float* b1b = (const float*)d_in[6];
    const float* W2a = (const float*)d_in[7];
    const float* b2a = (const float*)d_in[8];
    const float* W2b = (const float*)d_in[9];
    const float* b2b = (const float*)d_in[10];
    const float* Wf1 = (const float*)d_in[11];
    const float* bf1 = (const float*)d_in[12];
    const float* Wf2 = (const float*)d_in[13];
    const float* bf2 = (const float*)d_in[14];

    int N   = in_sizes[0] / NF;        // 128000
    int E   = in_sizes[1] / 2;         // 2048000
    int Bn  = N / NPG;                 // 64 graphs
    int NC  = Bn * 4;                  // 256 chunks

    // workspace carve-up
    float* t1     = (float*)d_ws;                        // N*8        4.1 MB
    float* u      = t1 + (size_t)N * HD;                 // N*8        4.1 MB
    int*   gcol   = (int*)(u + (size_t)N * HD);          // E          8.2 MB
    int*   rpc    = gcol + (size_t)E;                    // NC*(NPG+1) 2.0 MB
    float* bparts = (float*)(rpc + (size_t)NC * (NPG + 1) + 16);  // 256*2

    k_featsort<<<NC + N / 64, 256, 0, stream>>>(x, W1a, ei, t1, gcol, rpc,
                                                N, E, NC);
    k_l1 <<<NC, 512, 0, stream>>>(t1, rpc, gcol, u, b1a, W1b, b1b, W2a);
    k_l2 <<<NC, 512, 0, stream>>>(u, rpc, gcol, b2a, W2b, b2b, Wf1, bf1,
                                  Wf2, bparts);
    k_fin<<<1, 64, 0, stream>>>(bparts, bf2, (float*)d_out, Bn);
}

// Round 13
// 161.454 us; speedup vs baseline: 1.1799x; 1.0487x over previous
//
#include <hip/hip_runtime.h>
#include <math.h>

#define NF 128
#define HD 8
#define NPG 2000          // nodes per graph
#define EPB 8000          // edges per sort chunk (4 chunks per graph)
#define NPB 500           // nodes per layer block (4 blocks/graph)
#define FNPB 128          // nodes per feat block (1024 thr)
#define SLOPE 0.01f

__device__ __forceinline__ float lrelu(float v) {
    return v > 0.0f ? v : SLOPE * v;
}

// ---------------------------------------------------------------------------
// K1: fused [sort blocks 0..255 (R10-proven 1024-thr body)] +
//          [feat blocks 256..1255: 128 nodes each, thread=(node,col)].
// Disjoint I/O -> concurrent. Sort first: latency-bound waves overlap feat's
// VALU-bound waves. Union LDS 71.7 KB -> 2 blocks/CU, 32 waves/CU.
// ---------------------------------------------------------------------------
__global__ __launch_bounds__(1024) void k_featsort(
    const float* __restrict__ x, const float* __restrict__ W1a,
    const int* __restrict__ ei, float* __restrict__ t1,
    int* __restrict__ gcol, int* __restrict__ rpc, int N, int E, int NC)
{
    __shared__ union {
        struct { float tile[FNPB * 132]; float wl[NF * HD]; } f;          // 71.7 KB
        struct { int cnt[NPG]; int srt[EPB]; int wtot[16]; int wpre[16]; } s; // 40.2 KB
    } sm;

    const int tid = threadIdx.x;

    if ((int)blockIdx.x < NC) {
        // ---------------- sort chunk b (R10 k_sort body) ----------------
        const int b = blockIdx.x;
        const int g = b >> 2;
        const int lane = tid & 63;
        const int wv = tid >> 6;
        const int nodeBase = g * NPG;
        const int e0 = b * EPB;

        for (int i = tid; i < NPG; i += 1024) sm.s.cnt[i] = 0;
        __syncthreads();

        for (int e = e0 + tid; e < e0 + EPB; e += 1024) {
            int dl = ei[E + e] - nodeBase;
            atomicAdd(&sm.s.cnt[dl], 1);              // native ds_add_u32
        }
        __syncthreads();

        int c0 = 0, c1 = 0;
        if (tid < 1000) { c0 = sm.s.cnt[2 * tid]; c1 = sm.s.cnt[2 * tid + 1]; }
        int s = c0 + c1;
        int isc = s;
#pragma unroll
        for (int d = 1; d < 64; d <<= 1) {
            int o = __shfl_up(isc, d);
            if (lane >= d) isc += o;
        }
        if (lane == 63) sm.s.wtot[wv] = isc;
        __syncthreads();
        if (wv == 0) {
            int v = (lane < 16) ? sm.s.wtot[lane] : 0;
            int iv = v;
#pragma unroll
            for (int d = 1; d < 16; d <<= 1) {
                int o = __shfl_up(iv, d);
                if (lane >= d) iv += o;
            }
            if (lane < 16) sm.s.wpre[lane] = iv - v;
        }
        __syncthreads();
        int excl = isc - s + sm.s.wpre[wv];

        int* rpb = rpc + (size_t)b * (NPG + 1);
        if (tid < 1000) {
            sm.s.cnt[2 * tid]     = excl;
            sm.s.cnt[2 * tid + 1] = excl + c0;
            rpb[2 * tid]     = excl;
            rpb[2 * tid + 1] = excl + c0;
        }
        if (tid == 0) rpb[NPG] = EPB;
        __syncthreads();

        for (int e = e0 + tid; e < e0 + EPB; e += 1024) {
            int src = ei[e] - nodeBase;               // LOCAL src
            int dl = ei[E + e] - nodeBase;
            int pos = atomicAdd(&sm.s.cnt[dl], 1);    // ds_add_rtn_u32
            sm.s.srt[pos] = src;
        }
        __syncthreads();

        int4* dst4 = (int4*)(gcol + (size_t)b * EPB);
        const int4* s4 = (const int4*)sm.s.srt;
        for (int i = tid; i < EPB / 4; i += 1024) dst4[i] = s4[i];
    } else {
        // ---------------- feat block: 128 nodes ----------------
        const size_t base = (size_t)(blockIdx.x - NC) * FNPB;

        if (tid < 256) ((float4*)sm.f.wl)[tid] = ((const float4*)W1a)[tid];

        const float4* xg = (const float4*)(x + base * NF);
#pragma unroll
        for (int i = 0; i < 4; ++i) {
            int idx = tid + i * 1024;                 // 0..4095
            float4 v = xg[idx];
            int n = idx >> 5;                         // node (32 float4/row)
            int k4 = idx & 31;
            *(float4*)(sm.f.tile + n * 132 + k4 * 4) = v;
        }
        __syncthreads();

        const int n = tid >> 3;                       // 0..127
        const int col = tid & 7;
        float acc = 0.0f;
        const float* row = sm.f.tile + n * 132;
#pragma unroll
        for (int k4 = 0; k4 < 32; ++k4) {
            float4 r = *(const float4*)(row + k4 * 4);
            int kb = k4 * 4 * HD + col;
            acc += r.x * sm.f.wl[kb];
            acc += r.y * sm.f.wl[kb + HD];
            acc += r.z * sm.f.wl[kb + 2 * HD];
            acc += r.w * sm.f.wl[kb + 3 * HD];
        }
        t1[(base + n) * HD + col] = acc;              // fully coalesced
    }
}

// ---------------------------------------------------------------------------
// K2: layer 1 (R10-proven). 4 blocks/graph x 512 thr. Stage graph's t1 slice
// into split LDS tables lo4/hi4, 1 node/thread gather + MLP1 + u = h@W2a.
// No min-waves bound (R11: forcing VGPR<=64 regressed).
// ---------------------------------------------------------------------------
__global__ __launch_bounds__(512) void k_l1(
    const float* __restrict__ t1, const int* __restrict__ rpc,
    const int* __restrict__ gcol, float* __restrict__ u,
    const float* __restrict__ b1a, const float* __restrict__ W1b,
    const float* __restrict__ b1b, const float* __restrict__ W2a)
{
    __shared__ float tbl[NPG * HD];   // 62.5 KiB: lo4[2000] then hi4[2000]
    __shared__ float wts[144];        // b1a[8] W1b[64] b1b[8] W2a[64]

    const int b = blockIdx.x;
    const int g = b >> 2;
    const int q = b & 3;
    const int tid = threadIdx.x;

    if (tid < 144) {
        float v;
        if (tid < 8)       v = b1a[tid];
        else if (tid < 72) v = W1b[tid - 8];
        else if (tid < 80) v = b1b[tid - 72];
        else               v = W2a[tid - 80];
        wts[tid] = v;
    }

    const float4* src4 = (const float4*)(t1 + (size_t)g * NPG * HD);
    float4* lo4 = (float4*)tbl;
    float4* hi4 = lo4 + NPG;
#pragma unroll
    for (int i = 0; i < 8; ++i) {
        int idx = tid + i * 512;
        if (idx < 2 * NPG) {
            float4 v = src4[idx];
            int n = idx >> 1;
            if (idx & 1) hi4[n] = v; else lo4[n] = v;
        }
    }
    __syncthreads();

    if (tid < NPB) {
        const int nl = q * NPB + tid;
        float a0 = 0, a1 = 0, a2 = 0, a3 = 0, a4 = 0, a5 = 0, a6 = 0, a7 = 0;
#pragma unroll
        for (int p = 0; p < 4; ++p) {
            const int* rpb  = rpc + (size_t)((g << 2) + p) * (NPG + 1);
            const int* colp = gcol + (size_t)((g << 2) + p) * EPB;
            int rs = rpb[nl], re = rpb[nl + 1];
            for (int e = rs; e < re; ++e) {
                int sl = colp[e];
                float4 pa = lo4[sl];
                float4 pb = hi4[sl];
                a0 += pa.x; a1 += pa.y; a2 += pa.z; a3 += pa.w;
                a4 += pb.x; a5 += pb.y; a6 += pb.z; a7 += pb.w;
            }
        }
        float4 tA = lo4[nl], tB = hi4[nl];     // self feature
        float z[HD];
        z[0] = lrelu(tA.x + a0 + wts[0]); z[1] = lrelu(tA.y + a1 + wts[1]);
        z[2] = lrelu(tA.z + a2 + wts[2]); z[3] = lrelu(tA.w + a3 + wts[3]);
        z[4] = lrelu(tB.x + a4 + wts[4]); z[5] = lrelu(tB.y + a5 + wts[5]);
        z[6] = lrelu(tB.z + a6 + wts[6]); z[7] = lrelu(tB.w + a7 + wts[7]);

        float h[HD];
#pragma unroll
        for (int j = 0; j < HD; ++j) {
            float acc = wts[72 + j];
#pragma unroll
            for (int c = 0; c < HD; ++c) acc += z[c] * wts[8 + c * HD + j];
            h[j] = lrelu(acc);
        }
        float uu[HD];
#pragma unroll
        for (int j = 0; j < HD; ++j) {
            float acc = 0.0f;
#pragma unroll
            for (int c = 0; c < HD; ++c) acc += h[c] * wts[80 + c * HD + j];
            uu[j] = acc;
        }
        float* ur = u + ((size_t)g * NPG + nl) * HD;
        *(float4*)ur       = make_float4(uu[0], uu[1], uu[2], uu[3]);
        *(float4*)(ur + 4) = make_float4(uu[4], uu[5], uu[6], uu[7]);
    }
}

// ---------------------------------------------------------------------------
// K3: layer 2 (R10 structure). MLP2 + FC1 + FC2 partials; plain-store
// per-block partial (no device-scope sync — R6 lesson). k_fin finalizes.
// ---------------------------------------------------------------------------
__global__ __launch_bounds__(512) void k_l2(
    const float* __restrict__ u, const int* __restrict__ rpc,
    const int* __restrict__ gcol,
    const float* __restrict__ b2a, const float* __restrict__ W2b,
    const float* __restrict__ b2b, const float* __restrict__ Wf1,
    const float* __restrict__ bf1, const float* __restrict__ Wf2,
    float* __restrict__ bparts)
{
    __shared__ float tbl[NPG * HD];   // 62.5 KiB split tables
    __shared__ float wts[89];         // b2a[8] W2b[64] b2b[8] Wf1[8] bf1[1]
    __shared__ float red[16];

    const int b = blockIdx.x;
    const int g = b >> 2;
    const int q = b & 3;
    const int tid = threadIdx.x;
    const int lane = tid & 63;
    const int wv = tid >> 6;

    if (tid < 89) {
        float v;
        if (tid < 8)       v = b2a[tid];
        else if (tid < 72) v = W2b[tid - 8];
        else if (tid < 80) v = b2b[tid - 72];
        else if (tid < 88) v = Wf1[tid - 80];
        else               v = bf1[0];
        wts[tid] = v;
    }

    const float4* src4 = (const float4*)(u + (size_t)g * NPG * HD);
    float4* lo4 = (float4*)tbl;
    float4* hi4 = lo4 + NPG;
#pragma unroll
    for (int i = 0; i < 8; ++i) {
        int idx = tid + i * 512;
        if (idx < 2 * NPG) {
            float4 v = src4[idx];
            int n = idx >> 1;
            if (idx & 1) hi4[n] = v; else lo4[n] = v;
        }
    }
    __syncthreads();

    float acc0 = 0.0f, acc1 = 0.0f;
    if (tid < NPB) {
        const int nl = q * NPB + tid;
        float a0 = 0, a1 = 0, a2 = 0, a3 = 0, a4 = 0, a5 = 0, a6 = 0, a7 = 0;
#pragma unroll
        for (int p = 0; p < 4; ++p) {
            const int* rpb  = rpc + (size_t)((g << 2) + p) * (NPG + 1);
            const int* colp = gcol + (size_t)((g << 2) + p) * EPB;
            int rs = rpb[nl], re = rpb[nl + 1];
            for (int e = rs; e < re; ++e) {
                int sl = colp[e];
                float4 pa = lo4[sl];
                float4 pb = hi4[sl];
                a0 += pa.x; a1 += pa.y; a2 += pa.z; a3 += pa.w;
                a4 += pb.x; a5 += pb.y; a6 += pb.z; a7 += pb.w;
            }
        }
        float4 uA = lo4[nl], uB = hi4[nl];
        float z[HD];
        z[0] = lrelu(uA.x + a0 + wts[0]); z[1] = lrelu(uA.y + a1 + wts[1]);
        z[2] = lrelu(uA.z + a2 + wts[2]); z[3] = lrelu(uA.w + a3 + wts[3]);
        z[4] = lrelu(uB.x + a4 + wts[4]); z[5] = lrelu(uB.y + a5 + wts[5]);
        z[6] = lrelu(uB.z + a6 + wts[6]); z[7] = lrelu(uB.w + a7 + wts[7]);

        float sv = wts[88];
#pragma unroll
        for (int j = 0; j < HD; ++j) {
            float acc = wts[72 + j];
#pragma unroll
            for (int c = 0; c < HD; ++c) acc += z[c] * wts[8 + c * HD + j];
            sv += lrelu(acc) * wts[80 + j];
        }
        float pf = lrelu(sv);
        float2 wf = *(const float2*)(Wf2 + (size_t)nl * 2);
        acc0 = pf * wf.x;
        acc1 = pf * wf.y;
    }

#pragma unroll
    for (int off = 32; off > 0; off >>= 1) {
        acc0 += __shfl_down(acc0, off);
        acc1 += __shfl_down(acc1, off);
    }
    if (lane == 0) { red[wv * 2] = acc0; red[wv * 2 + 1] = acc1; }
    __syncthreads();

    if (tid == 0) {
        float y0 = 0.f, y1 = 0.f;
#pragma unroll
        for (int w = 0; w < 8; ++w) { y0 += red[w * 2]; y1 += red[w * 2 + 1]; }
        *(float2*)(bparts + (size_t)b * 2) = make_float2(y0, y1);
    }
}

// ---------------------------------------------------------------------------
// K4: finalize — one thread per graph sums 4 block partials, log_softmax.
// ---------------------------------------------------------------------------
__global__ __launch_bounds__(64) void k_fin(const float* __restrict__ bparts,
                                            const float* __restrict__ bf2,
                                            float* __restrict__ out, int Bn) {
    int g = threadIdx.x;
    if (g >= Bn) return;
    float y0 = bf2[0], y1 = bf2[1];
#pragma unroll
    for (int b = 0; b < 4; ++b) {
        float2 v = *(const float2*)(bparts + (size_t)(g * 4 + b) * 2);
        y0 += v.x; y1 += v.y;
    }
    float m = fmaxf(y0, y1);
    float lse = m + logf(expf(y0 - m) + expf(y1 - m));
    out[g * 2 + 0] = y0 - lse;
    out[g * 2 + 1] = y1 - lse;
}

// ---------------------------------------------------------------------------
extern "C" void kernel_launch(void* const* d_in, const int* in_sizes, int n_in,
                              void* d_out, int out_size, void* d_ws, size_t ws_size,
                              hipStream_t stream) {
    const float* x   = (const float*)d_in[0];
    const int*   ei  = (const int*)  d_in[1];
    const float* W1a = (const float*)d_in[3];
    const float* b1a = (const float*)d_in[4];
    const float* W1b = (const float*)d_in[5];
    const float* b1b = (const float*)d_in[6];
    const float* W2a = (const float*)d_in[7];
    const float* b2a = (const float*)d_in[8];
    const float* W2b = (const float*)d_in[9];
    const float* b2b = (const float*)d_in[10];
    const float* Wf1 = (const float*)d_in[11];
    const float* bf1 = (const float*)d_in[12];
    const float* Wf2 = (const float*)d_in[13];
    const float* bf2 = (const float*)d_in[14];

    int N   = in_sizes[0] / NF;        // 128000
    int E   = in_sizes[1] / 2;         // 2048000
    int Bn  = N / NPG;                 // 64 graphs
    int NC  = Bn * 4;                  // 256 chunks

    // workspace carve-up
    float* t1     = (float*)d_ws;                        // N*8        4.1 MB
    float* u      = t1 + (size_t)N * HD;                 // N*8        4.1 MB
    int*   gcol   = (int*)(u + (size_t)N * HD);          // E          8.2 MB
    int*   rpc    = gcol + (size_t)E;                    // NC*(NPG+1) 2.0 MB
    float* bparts = (float*)(rpc + (size_t)NC * (NPG + 1) + 16);  // 256*2

    k_featsort<<<NC + N / FNPB, 1024, 0, stream>>>(x, W1a, ei, t1, gcol, rpc,
                                                   N, E, NC);
    k_l1 <<<NC, 512, 0, stream>>>(t1, rpc, gcol, u, b1a, W1b, b1b, W2a);
    k_l2 <<<NC, 512, 0, stream>>>(u, rpc, gcol, b2a, W2b, b2b, Wf1, bf1,
                                  Wf2, bparts);
    k_fin<<<1, 64, 0, stream>>>(bparts, bf2, (float*)d_out, Bn);
}

// Round 14
// 159.126 us; speedup vs baseline: 1.1972x; 1.0146x over previous
//
#include <hip/hip_runtime.h>
#include <math.h>

#define NF 128
#define HD 8
#define NPG 2000          // nodes per graph
#define EPB 8000          // edges per sort chunk (4 chunks per graph)
#define NPB 500           // nodes per layer block (4 blocks/graph)
#define FNPB 128          // nodes per feat block (1024 thr)
#define SLOPE 0.01f

__device__ __forceinline__ float lrelu(float v) {
    return v > 0.0f ? v : SLOPE * v;
}
// bf16 helpers: RNE pack, cheap unpack (<<16 / mask)
__device__ __forceinline__ unsigned short f2bf(float f) {
    unsigned int u = __float_as_uint(f);
    return (unsigned short)((u + 0x7FFFu + ((u >> 16) & 1u)) >> 16);
}
__device__ __forceinline__ float bfl(unsigned int p) {   // low bf16 of packed pair
    return __uint_as_float(p << 16);
}
__device__ __forceinline__ float bfh(unsigned int p) {   // high bf16
    return __uint_as_float(p & 0xFFFF0000u);
}

// ---------------------------------------------------------------------------
// K1: fused [sort 0..255 (1024-thr R13 body, ushort col dump)] +
//          [feat 256..1255: 128 nodes, thread=(node,col), bf16 t1 store].
// ---------------------------------------------------------------------------
__global__ __launch_bounds__(1024) void k_featsort(
    const float* __restrict__ x, const float* __restrict__ W1a,
    const int* __restrict__ ei, unsigned short* __restrict__ t1b,
    unsigned short* __restrict__ gcolb, int* __restrict__ rpc,
    int N, int E, int NC)
{
    __shared__ union {
        struct { float tile[FNPB * 132]; float wl[NF * HD]; } f;          // 71.7 KB
        struct { int cnt[NPG]; int srt[EPB]; int wtot[16]; int wpre[16]; } s; // 40.2 KB
    } sm;

    const int tid = threadIdx.x;

    if ((int)blockIdx.x < NC) {
        // ---------------- sort chunk b ----------------
        const int b = blockIdx.x;
        const int g = b >> 2;
        const int lane = tid & 63;
        const int wv = tid >> 6;
        const int nodeBase = g * NPG;
        const int e0 = b * EPB;

        for (int i = tid; i < NPG; i += 1024) sm.s.cnt[i] = 0;
        __syncthreads();

        for (int e = e0 + tid; e < e0 + EPB; e += 1024) {
            int dl = ei[E + e] - nodeBase;
            atomicAdd(&sm.s.cnt[dl], 1);              // native ds_add_u32
        }
        __syncthreads();

        int c0 = 0, c1 = 0;
        if (tid < 1000) { c0 = sm.s.cnt[2 * tid]; c1 = sm.s.cnt[2 * tid + 1]; }
        int s = c0 + c1;
        int isc = s;
#pragma unroll
        for (int d = 1; d < 64; d <<= 1) {
            int o = __shfl_up(isc, d);
            if (lane >= d) isc += o;
        }
        if (lane == 63) sm.s.wtot[wv] = isc;
        __syncthreads();
        if (wv == 0) {
            int v = (lane < 16) ? sm.s.wtot[lane] : 0;
            int iv = v;
#pragma unroll
            for (int d = 1; d < 16; d <<= 1) {
                int o = __shfl_up(iv, d);
                if (lane >= d) iv += o;
            }
            if (lane < 16) sm.s.wpre[lane] = iv - v;
        }
        __syncthreads();
        int excl = isc - s + sm.s.wpre[wv];

        int* rpb = rpc + (size_t)b * (NPG + 1);
        if (tid < 1000) {
            sm.s.cnt[2 * tid]     = excl;
            sm.s.cnt[2 * tid + 1] = excl + c0;
            rpb[2 * tid]     = excl;
            rpb[2 * tid + 1] = excl + c0;
        }
        if (tid == 0) rpb[NPG] = EPB;
        __syncthreads();

        for (int e = e0 + tid; e < e0 + EPB; e += 1024) {
            int src = ei[e] - nodeBase;               // LOCAL src (<2000)
            int dl = ei[E + e] - nodeBase;
            int pos = atomicAdd(&sm.s.cnt[dl], 1);    // ds_add_rtn_u32
            sm.s.srt[pos] = src;
        }
        __syncthreads();

        // coalesced dump as ushort (pack 2 per uint)
        unsigned int* dst = (unsigned int*)(gcolb + (size_t)b * EPB);
        for (int i = tid; i < EPB / 2; i += 1024) {
            unsigned int lo = (unsigned int)sm.s.srt[2 * i] & 0xFFFFu;
            unsigned int hi = (unsigned int)sm.s.srt[2 * i + 1] << 16;
            dst[i] = lo | hi;
        }
    } else {
        // ---------------- feat block: 128 nodes ----------------
        const size_t base = (size_t)(blockIdx.x - NC) * FNPB;

        if (tid < 256) ((float4*)sm.f.wl)[tid] = ((const float4*)W1a)[tid];

        const float4* xg = (const float4*)(x + base * NF);
#pragma unroll
        for (int i = 0; i < 4; ++i) {
            int idx = tid + i * 1024;                 // 0..4095
            float4 v = xg[idx];
            int n = idx >> 5;
            int k4 = idx & 31;
            *(float4*)(sm.f.tile + n * 132 + k4 * 4) = v;
        }
        __syncthreads();

        const int n = tid >> 3;
        const int col = tid & 7;
        float acc = 0.0f;
        const float* row = sm.f.tile + n * 132;
#pragma unroll
        for (int k4 = 0; k4 < 32; ++k4) {
            float4 r = *(const float4*)(row + k4 * 4);
            int kb = k4 * 4 * HD + col;
            acc += r.x * sm.f.wl[kb];
            acc += r.y * sm.f.wl[kb + HD];
            acc += r.z * sm.f.wl[kb + 2 * HD];
            acc += r.w * sm.f.wl[kb + 3 * HD];
        }
        t1b[(base + n) * HD + col] = f2bf(acc);       // coalesced 2B stores
    }
}

// ---------------------------------------------------------------------------
// K2: layer 1. 4 blocks/graph x 512 thr (R10/R13-proven decomposition).
// bf16 table: uint4[2000] = 32 KB LDS; ONE ds_read_b128 per edge (was two).
// fp32 accumulate + MLP; bf16 RNE pack of u.
// ---------------------------------------------------------------------------
__global__ __launch_bounds__(512) void k_l1(
    const unsigned short* __restrict__ t1b, const int* __restrict__ rpc,
    const unsigned short* __restrict__ gcolb, unsigned short* __restrict__ ub,
    const float* __restrict__ b1a, const float* __restrict__ W1b,
    const float* __restrict__ b1b, const float* __restrict__ W2a)
{
    __shared__ uint4 tbl[NPG];        // 32 KB (8 bf16 per node)
    __shared__ float wts[144];        // b1a[8] W1b[64] b1b[8] W2a[64]

    const int b = blockIdx.x;
    const int g = b >> 2;
    const int q = b & 3;
    const int tid = threadIdx.x;

    if (tid < 144) {
        float v;
        if (tid < 8)       v = b1a[tid];
        else if (tid < 72) v = W1b[tid - 8];
        else if (tid < 80) v = b1b[tid - 72];
        else               v = W2a[tid - 80];
        wts[tid] = v;
    }

    const uint4* src4 = (const uint4*)(t1b + (size_t)g * NPG * HD);
#pragma unroll
    for (int i = 0; i < 4; ++i) {
        int idx = tid + i * 512;
        if (idx < NPG) tbl[idx] = src4[idx];
    }
    __syncthreads();

    if (tid < NPB) {
        const int nl = q * NPB + tid;
        float a0 = 0, a1 = 0, a2 = 0, a3 = 0, a4 = 0, a5 = 0, a6 = 0, a7 = 0;
#pragma unroll
        for (int p = 0; p < 4; ++p) {
            const int* rpb = rpc + (size_t)((g << 2) + p) * (NPG + 1);
            const unsigned short* colp = gcolb + (size_t)((g << 2) + p) * EPB;
            int rs = rpb[nl], re = rpb[nl + 1];
            for (int e = rs; e < re; ++e) {
                int sl = colp[e];
                uint4 v = tbl[sl];                    // one b128 per edge
                a0 += bfl(v.x); a1 += bfh(v.x);
                a2 += bfl(v.y); a3 += bfh(v.y);
                a4 += bfl(v.z); a5 += bfh(v.z);
                a6 += bfl(v.w); a7 += bfh(v.w);
            }
        }
        uint4 sv = tbl[nl];                           // self feature
        float z[HD];
        z[0] = lrelu(bfl(sv.x) + a0 + wts[0]); z[1] = lrelu(bfh(sv.x) + a1 + wts[1]);
        z[2] = lrelu(bfl(sv.y) + a2 + wts[2]); z[3] = lrelu(bfh(sv.y) + a3 + wts[3]);
        z[4] = lrelu(bfl(sv.z) + a4 + wts[4]); z[5] = lrelu(bfh(sv.z) + a5 + wts[5]);
        z[6] = lrelu(bfl(sv.w) + a6 + wts[6]); z[7] = lrelu(bfh(sv.w) + a7 + wts[7]);

        float h[HD];
#pragma unroll
        for (int j = 0; j < HD; ++j) {
            float acc = wts[72 + j];
#pragma unroll
            for (int c = 0; c < HD; ++c) acc += z[c] * wts[8 + c * HD + j];
            h[j] = lrelu(acc);
        }
        float uu[HD];
#pragma unroll
        for (int j = 0; j < HD; ++j) {
            float acc = 0.0f;
#pragma unroll
            for (int c = 0; c < HD; ++c) acc += h[c] * wts[80 + c * HD + j];
            uu[j] = acc;
        }
        uint4 pk;
        pk.x = (unsigned int)f2bf(uu[0]) | ((unsigned int)f2bf(uu[1]) << 16);
        pk.y = (unsigned int)f2bf(uu[2]) | ((unsigned int)f2bf(uu[3]) << 16);
        pk.z = (unsigned int)f2bf(uu[4]) | ((unsigned int)f2bf(uu[5]) << 16);
        pk.w = (unsigned int)f2bf(uu[6]) | ((unsigned int)f2bf(uu[7]) << 16);
        ((uint4*)ub)[(size_t)g * NPG + nl] = pk;      // coalesced 16B store
    }
}

// ---------------------------------------------------------------------------
// K3: layer 2 (same structure over ub). MLP2 + FC1 + FC2 partials;
// plain-store per-block partial (no device-scope sync — R6). k_fin finalizes.
// ---------------------------------------------------------------------------
__global__ __launch_bounds__(512) void k_l2(
    const unsigned short* __restrict__ ub, const int* __restrict__ rpc,
    const unsigned short* __restrict__ gcolb,
    const float* __restrict__ b2a, const float* __restrict__ W2b,
    const float* __restrict__ b2b, const float* __restrict__ Wf1,
    const float* __restrict__ bf1, const float* __restrict__ Wf2,
    float* __restrict__ bparts)
{
    __shared__ uint4 tbl[NPG];        // 32 KB
    __shared__ float wts[89];         // b2a[8] W2b[64] b2b[8] Wf1[8] bf1[1]
    __shared__ float red[16];

    const int b = blockIdx.x;
    const int g = b >> 2;
    const int q = b & 3;
    const int tid = threadIdx.x;
    const int lane = tid & 63;
    const int wv = tid >> 6;

    if (tid < 89) {
        float v;
        if (tid < 8)       v = b2a[tid];
        else if (tid < 72) v = W2b[tid - 8];
        else if (tid < 80) v = b2b[tid - 72];
        else if (tid < 88) v = Wf1[tid - 80];
        else               v = bf1[0];
        wts[tid] = v;
    }

    const uint4* src4 = (const uint4*)(ub + (size_t)g * NPG * HD);
#pragma unroll
    for (int i = 0; i < 4; ++i) {
        int idx = tid + i * 512;
        if (idx < NPG) tbl[idx] = src4[idx];
    }
    __syncthreads();

    float acc0 = 0.0f, acc1 = 0.0f;
    if (tid < NPB) {
        const int nl = q * NPB + tid;
        float a0 = 0, a1 = 0, a2 = 0, a3 = 0, a4 = 0, a5 = 0, a6 = 0, a7 = 0;
#pragma unroll
        for (int p = 0; p < 4; ++p) {
            const int* rpb = rpc + (size_t)((g << 2) + p) * (NPG + 1);
            const unsigned short* colp = gcolb + (size_t)((g << 2) + p) * EPB;
            int rs = rpb[nl], re = rpb[nl + 1];
            for (int e = rs; e < re; ++e) {
                int sl = colp[e];
                uint4 v = tbl[sl];
                a0 += bfl(v.x); a1 += bfh(v.x);
                a2 += bfl(v.y); a3 += bfh(v.y);
                a4 += bfl(v.z); a5 += bfh(v.z);
                a6 += bfl(v.w); a7 += bfh(v.w);
            }
        }
        uint4 sv = tbl[nl];
        float z[HD];
        z[0] = lrelu(bfl(sv.x) + a0 + wts[0]); z[1] = lrelu(bfh(sv.x) + a1 + wts[1]);
        z[2] = lrelu(bfl(sv.y) + a2 + wts[2]); z[3] = lrelu(bfh(sv.y) + a3 + wts[3]);
        z[4] = lrelu(bfl(sv.z) + a4 + wts[4]); z[5] = lrelu(bfh(sv.z) + a5 + wts[5]);
        z[6] = lrelu(bfl(sv.w) + a6 + wts[6]); z[7] = lrelu(bfh(sv.w) + a7 + wts[7]);

        float svl = wts[88];
#pragma unroll
        for (int j = 0; j < HD; ++j) {
            float acc = wts[72 + j];
#pragma unroll
            for (int c = 0; c < HD; ++c) acc += z[c] * wts[8 + c * HD + j];
            svl += lrelu(acc) * wts[80 + j];
        }
        float pf = lrelu(svl);
        float2 wf = *(const float2*)(Wf2 + (size_t)nl * 2);
        acc0 = pf * wf.x;
        acc1 = pf * wf.y;
    }

#pragma unroll
    for (int off = 32; off > 0; off >>= 1) {
        acc0 += __shfl_down(acc0, off);
        acc1 += __shfl_down(acc1, off);
    }
    if (lane == 0) { red[wv * 2] = acc0; red[wv * 2 + 1] = acc1; }
    __syncthreads();

    if (tid == 0) {
        float y0 = 0.f, y1 = 0.f;
#pragma unroll
        for (int w = 0; w < 8; ++w) { y0 += red[w * 2]; y1 += red[w * 2 + 1]; }
        *(float2*)(bparts + (size_t)b * 2) = make_float2(y0, y1);
    }
}

// ---------------------------------------------------------------------------
// K4: finalize — one thread per graph sums 4 block partials, log_softmax.
// ---------------------------------------------------------------------------
__global__ __launch_bounds__(64) void k_fin(const float* __restrict__ bparts,
                                            const float* __restrict__ bf2,
                                            float* __restrict__ out, int Bn) {
    int g = threadIdx.x;
    if (g >= Bn) return;
    float y0 = bf2[0], y1 = bf2[1];
#pragma unroll
    for (int b = 0; b < 4; ++b) {
        float2 v = *(const float2*)(bparts + (size_t)(g * 4 + b) * 2);
        y0 += v.x; y1 += v.y;
    }
    float m = fmaxf(y0, y1);
    float lse = m + logf(expf(y0 - m) + expf(y1 - m));
    out[g * 2 + 0] = y0 - lse;
    out[g * 2 + 1] = y1 - lse;
}

// ---------------------------------------------------------------------------
extern "C" void kernel_launch(void* const* d_in, const int* in_sizes, int n_in,
                              void* d_out, int out_size, void* d_ws, size_t ws_size,
                              hipStream_t stream) {
    const float* x   = (const float*)d_in[0];
    const int*   ei  = (const int*)  d_in[1];
    const float* W1a = (const float*)d_in[3];
    const float* b1a = (const float*)d_in[4];
    const float* W1b = (const float*)d_in[5];
    const float* b1b = (const float*)d_in[6];
    const float* W2a = (const float*)d_in[7];
    const float* b2a = (const float*)d_in[8];
    const float* W2b = (const float*)d_in[9];
    const float* b2b = (const float*)d_in[10];
    const float* Wf1 = (const float*)d_in[11];
    const float* bf1 = (const float*)d_in[12];
    const float* Wf2 = (const float*)d_in[13];
    const float* bf2 = (const float*)d_in[14];

    int N   = in_sizes[0] / NF;        // 128000
    int E   = in_sizes[1] / 2;         // 2048000
    int Bn  = N / NPG;                 // 64 graphs
    int NC  = Bn * 4;                  // 256 chunks

    // workspace carve-up (16B-aligned sections)
    unsigned short* t1b   = (unsigned short*)d_ws;              // N*8 bf16  2.0 MB
    unsigned short* ubuf  = t1b + (size_t)N * HD;               // N*8 bf16  2.0 MB
    unsigned short* gcolb = ubuf + (size_t)N * HD;              // E ushort  4.1 MB
    int*            rpc   = (int*)(gcolb + (size_t)E);          // NC*(NPG+1) 2.0 MB
    float*          bparts= (float*)(rpc + (size_t)NC * (NPG + 1) + 16); // 256*2

    k_featsort<<<NC + N / FNPB, 1024, 0, stream>>>(x, W1a, ei, t1b, gcolb, rpc,
                                                   N, E, NC);
    k_l1 <<<NC, 512, 0, stream>>>(t1b, rpc, gcolb, ubuf, b1a, W1b, b1b, W2a);
    k_l2 <<<NC, 512, 0, stream>>>(ubuf, rpc, gcolb, b2a, W2b, b2b, Wf1, bf1,
                                  Wf2, bparts);
    k_fin<<<1, 64, 0, stream>>>(bparts, bf2, (float*)d_out, Bn);
}

// Round 15
// 154.353 us; speedup vs baseline: 1.2342x; 1.0309x over previous
//
#include <hip/hip_runtime.h>
#include <math.h>

#define NF 128
#define HD 8
#define NPG 2000          // nodes per graph
#define EPB 8000          // edges per sort chunk (4 chunks per graph)
#define NPB 500           // nodes per layer block (4 blocks/graph)
#define FNPB 128          // nodes per feat block (1024 thr)
#define SLOPE 0.01f

__device__ __forceinline__ float lrelu(float v) {
    return v > 0.0f ? v : SLOPE * v;
}
// bf16 helpers: RNE pack, cheap unpack (<<16 / mask)
__device__ __forceinline__ unsigned short f2bf(float f) {
    unsigned int u = __float_as_uint(f);
    return (unsigned short)((u + 0x7FFFu + ((u >> 16) & 1u)) >> 16);
}
__device__ __forceinline__ float bfl(unsigned int p) {
    return __uint_as_float(p << 16);
}
__device__ __forceinline__ float bfh(unsigned int p) {
    return __uint_as_float(p & 0xFFFF0000u);
}

// ---------------------------------------------------------------------------
// K1: fused [sort 0..255 (1024-thr body, ushort col dump)] +
//          [feat 256..1255: 128 nodes, thread=(node,col), bf16 t1 store].
// (unchanged from R14)
// ---------------------------------------------------------------------------
__global__ __launch_bounds__(1024) void k_featsort(
    const float* __restrict__ x, const float* __restrict__ W1a,
    const int* __restrict__ ei, unsigned short* __restrict__ t1b,
    unsigned short* __restrict__ gcolb, int* __restrict__ rpc,
    int N, int E, int NC)
{
    __shared__ union {
        struct { float tile[FNPB * 132]; float wl[NF * HD]; } f;
        struct { int cnt[NPG]; int srt[EPB]; int wtot[16]; int wpre[16]; } s;
    } sm;

    const int tid = threadIdx.x;

    if ((int)blockIdx.x < NC) {
        const int b = blockIdx.x;
        const int g = b >> 2;
        const int lane = tid & 63;
        const int wv = tid >> 6;
        const int nodeBase = g * NPG;
        const int e0 = b * EPB;

        for (int i = tid; i < NPG; i += 1024) sm.s.cnt[i] = 0;
        __syncthreads();

        for (int e = e0 + tid; e < e0 + EPB; e += 1024) {
            int dl = ei[E + e] - nodeBase;
            atomicAdd(&sm.s.cnt[dl], 1);              // native ds_add_u32
        }
        __syncthreads();

        int c0 = 0, c1 = 0;
        if (tid < 1000) { c0 = sm.s.cnt[2 * tid]; c1 = sm.s.cnt[2 * tid + 1]; }
        int s = c0 + c1;
        int isc = s;
#pragma unroll
        for (int d = 1; d < 64; d <<= 1) {
            int o = __shfl_up(isc, d);
            if (lane >= d) isc += o;
        }
        if (lane == 63) sm.s.wtot[wv] = isc;
        __syncthreads();
        if (wv == 0) {
            int v = (lane < 16) ? sm.s.wtot[lane] : 0;
            int iv = v;
#pragma unroll
            for (int d = 1; d < 16; d <<= 1) {
                int o = __shfl_up(iv, d);
                if (lane >= d) iv += o;
            }
            if (lane < 16) sm.s.wpre[lane] = iv - v;
        }
        __syncthreads();
        int excl = isc - s + sm.s.wpre[wv];

        int* rpb = rpc + (size_t)b * (NPG + 1);
        if (tid < 1000) {
            sm.s.cnt[2 * tid]     = excl;
            sm.s.cnt[2 * tid + 1] = excl + c0;
            rpb[2 * tid]     = excl;
            rpb[2 * tid + 1] = excl + c0;
        }
        if (tid == 0) rpb[NPG] = EPB;
        __syncthreads();

        for (int e = e0 + tid; e < e0 + EPB; e += 1024) {
            int src = ei[e] - nodeBase;               // LOCAL src (<2000)
            int dl = ei[E + e] - nodeBase;
            int pos = atomicAdd(&sm.s.cnt[dl], 1);    // ds_add_rtn_u32
            sm.s.srt[pos] = src;
        }
        __syncthreads();

        unsigned int* dst = (unsigned int*)(gcolb + (size_t)b * EPB);
        for (int i = tid; i < EPB / 2; i += 1024) {
            unsigned int lo = (unsigned int)sm.s.srt[2 * i] & 0xFFFFu;
            unsigned int hi = (unsigned int)sm.s.srt[2 * i + 1] << 16;
            dst[i] = lo | hi;
        }
    } else {
        const size_t base = (size_t)(blockIdx.x - NC) * FNPB;

        if (tid < 256) ((float4*)sm.f.wl)[tid] = ((const float4*)W1a)[tid];

        const float4* xg = (const float4*)(x + base * NF);
#pragma unroll
        for (int i = 0; i < 4; ++i) {
            int idx = tid + i * 1024;
            float4 v = xg[idx];
            int n = idx >> 5;
            int k4 = idx & 31;
            *(float4*)(sm.f.tile + n * 132 + k4 * 4) = v;
        }
        __syncthreads();

        const int n = tid >> 3;
        const int col = tid & 7;
        float acc = 0.0f;
        const float* row = sm.f.tile + n * 132;
#pragma unroll
        for (int k4 = 0; k4 < 32; ++k4) {
            float4 r = *(const float4*)(row + k4 * 4);
            int kb = k4 * 4 * HD + col;
            acc += r.x * sm.f.wl[kb];
            acc += r.y * sm.f.wl[kb + HD];
            acc += r.z * sm.f.wl[kb + 2 * HD];
            acc += r.w * sm.f.wl[kb + 3 * HD];
        }
        t1b[(base + n) * HD + col] = f2bf(acc);
    }
}

// ---------------------------------------------------------------------------
// Batched gather core: per chunk, 8 independent clamped col loads then 8
// independent predicated LDS gathers (serial col->tbl chain broken); rare
// tail loop for degree > 8. Accumulation order per node == R14 (+0 terms).
// ---------------------------------------------------------------------------
#define GATHER_CHUNK(P)                                                       \
    {                                                                         \
        int b0 = rs[P], cnt = re[P] - b0;                                     \
        int sl[8];                                                            \
        _Pragma("unroll")                                                     \
        for (int j = 0; j < 8; ++j) {                                         \
            int idx = (j < cnt) ? (b0 + j) : 0;     /* safe addr */           \
            sl[j] = colp[P][idx];                                             \
        }                                                                     \
        _Pragma("unroll")                                                     \
        for (int j = 0; j < 8; ++j) {                                         \
            float w = (j < cnt) ? 1.0f : 0.0f;                                \
            uint4 v = tbl[sl[j]];                                             \
            a0 += w * bfl(v.x); a1 += w * bfh(v.x);                           \
            a2 += w * bfl(v.y); a3 += w * bfh(v.y);                           \
            a4 += w * bfl(v.z); a5 += w * bfh(v.z);                           \
            a6 += w * bfl(v.w); a7 += w * bfh(v.w);                           \
        }                                                                     \
        for (int e2 = b0 + 8; e2 < b0 + cnt; ++e2) {  /* rare tail */         \
            uint4 v = tbl[colp[P][e2]];                                       \
            a0 += bfl(v.x); a1 += bfh(v.x);                                   \
            a2 += bfl(v.y); a3 += bfh(v.y);                                   \
            a4 += bfl(v.z); a5 += bfh(v.z);                                   \
            a6 += bfl(v.w); a7 += bfh(v.w);                                   \
        }                                                                     \
    }

// ---------------------------------------------------------------------------
// K2: layer 1. 4 blocks/graph x 512 thr; bf16 uint4 table (32 KB LDS);
// batched gather; fp32 MLP; bf16 pack of u.
// ---------------------------------------------------------------------------
__global__ __launch_bounds__(512) void k_l1(
    const unsigned short* __restrict__ t1b, const int* __restrict__ rpc,
    const unsigned short* __restrict__ gcolb, unsigned short* __restrict__ ub,
    const float* __restrict__ b1a, const float* __restrict__ W1b,
    const float* __restrict__ b1b, const float* __restrict__ W2a)
{
    __shared__ uint4 tbl[NPG];        // 32 KB
    __shared__ float wts[144];        // b1a[8] W1b[64] b1b[8] W2a[64]

    const int b = blockIdx.x;
    const int g = b >> 2;
    const int q = b & 3;
    const int tid = threadIdx.x;

    if (tid < 144) {
        float v;
        if (tid < 8)       v = b1a[tid];
        else if (tid < 72) v = W1b[tid - 8];
        else if (tid < 80) v = b1b[tid - 72];
        else               v = W2a[tid - 80];
        wts[tid] = v;
    }

    const uint4* src4 = (const uint4*)(t1b + (size_t)g * NPG * HD);
#pragma unroll
    for (int i = 0; i < 4; ++i) {
        int idx = tid + i * 512;
        if (idx < NPG) tbl[idx] = src4[idx];
    }
    __syncthreads();

    if (tid < NPB) {
        const int nl = q * NPB + tid;
        int rs[4], re[4];
        const unsigned short* colp[4];
#pragma unroll
        for (int p = 0; p < 4; ++p) {
            const int* rpb = rpc + (size_t)((g << 2) + p) * (NPG + 1);
            colp[p] = gcolb + (size_t)((g << 2) + p) * EPB;
            rs[p] = rpb[nl]; re[p] = rpb[nl + 1];
        }
        float a0 = 0, a1 = 0, a2 = 0, a3 = 0, a4 = 0, a5 = 0, a6 = 0, a7 = 0;
        GATHER_CHUNK(0) GATHER_CHUNK(1) GATHER_CHUNK(2) GATHER_CHUNK(3)

        uint4 sv = tbl[nl];                           // self feature
        float z[HD];
        z[0] = lrelu(bfl(sv.x) + a0 + wts[0]); z[1] = lrelu(bfh(sv.x) + a1 + wts[1]);
        z[2] = lrelu(bfl(sv.y) + a2 + wts[2]); z[3] = lrelu(bfh(sv.y) + a3 + wts[3]);
        z[4] = lrelu(bfl(sv.z) + a4 + wts[4]); z[5] = lrelu(bfh(sv.z) + a5 + wts[5]);
        z[6] = lrelu(bfl(sv.w) + a6 + wts[6]); z[7] = lrelu(bfh(sv.w) + a7 + wts[7]);

        float h[HD];
#pragma unroll
        for (int j = 0; j < HD; ++j) {
            float acc = wts[72 + j];
#pragma unroll
            for (int c = 0; c < HD; ++c) acc += z[c] * wts[8 + c * HD + j];
            h[j] = lrelu(acc);
        }
        float uu[HD];
#pragma unroll
        for (int j = 0; j < HD; ++j) {
            float acc = 0.0f;
#pragma unroll
            for (int c = 0; c < HD; ++c) acc += h[c] * wts[80 + c * HD + j];
            uu[j] = acc;
        }
        uint4 pk;
        pk.x = (unsigned int)f2bf(uu[0]) | ((unsigned int)f2bf(uu[1]) << 16);
        pk.y = (unsigned int)f2bf(uu[2]) | ((unsigned int)f2bf(uu[3]) << 16);
        pk.z = (unsigned int)f2bf(uu[4]) | ((unsigned int)f2bf(uu[5]) << 16);
        pk.w = (unsigned int)f2bf(uu[6]) | ((unsigned int)f2bf(uu[7]) << 16);
        ((uint4*)ub)[(size_t)g * NPG + nl] = pk;
    }
}

// ---------------------------------------------------------------------------
// K3: layer 2 (batched gather over ub). MLP2 + FC1 + FC2 partials;
// plain-store per-block partial (no device-scope sync — R6). k_fin finalizes.
// ---------------------------------------------------------------------------
__global__ __launch_bounds__(512) void k_l2(
    const unsigned short* __restrict__ ub, const int* __restrict__ rpc,
    const unsigned short* __restrict__ gcolb,
    const float* __restrict__ b2a, const float* __restrict__ W2b,
    const float* __restrict__ b2b, const float* __restrict__ Wf1,
    const float* __restrict__ bf1, const float* __restrict__ Wf2,
    float* __restrict__ bparts)
{
    __shared__ uint4 tbl[NPG];        // 32 KB
    __shared__ float wts[89];         // b2a[8] W2b[64] b2b[8] Wf1[8] bf1[1]
    __shared__ float red[16];

    const int b = blockIdx.x;
    const int g = b >> 2;
    const int q = b & 3;
    const int tid = threadIdx.x;
    const int lane = tid & 63;
    const int wv = tid >> 6;

    if (tid < 89) {
        float v;
        if (tid < 8)       v = b2a[tid];
        else if (tid < 72) v = W2b[tid - 8];
        else if (tid < 80) v = b2b[tid - 72];
        else if (tid < 88) v = Wf1[tid - 80];
        else               v = bf1[0];
        wts[tid] = v;
    }

    const uint4* src4 = (const uint4*)(ub + (size_t)g * NPG * HD);
#pragma unroll
    for (int i = 0; i < 4; ++i) {
        int idx = tid + i * 512;
        if (idx < NPG) tbl[idx] = src4[idx];
    }
    __syncthreads();

    float acc0 = 0.0f, acc1 = 0.0f;
    if (tid < NPB) {
        const int nl = q * NPB + tid;
        int rs[4], re[4];
        const unsigned short* colp[4];
#pragma unroll
        for (int p = 0; p < 4; ++p) {
            const int* rpb = rpc + (size_t)((g << 2) + p) * (NPG + 1);
            colp[p] = gcolb + (size_t)((g << 2) + p) * EPB;
            rs[p] = rpb[nl]; re[p] = rpb[nl + 1];
        }
        float a0 = 0, a1 = 0, a2 = 0, a3 = 0, a4 = 0, a5 = 0, a6 = 0, a7 = 0;
        GATHER_CHUNK(0) GATHER_CHUNK(1) GATHER_CHUNK(2) GATHER_CHUNK(3)

        uint4 sv = tbl[nl];
        float z[HD];
        z[0] = lrelu(bfl(sv.x) + a0 + wts[0]); z[1] = lrelu(bfh(sv.x) + a1 + wts[1]);
        z[2] = lrelu(bfl(sv.y) + a2 + wts[2]); z[3] = lrelu(bfh(sv.y) + a3 + wts[3]);
        z[4] = lrelu(bfl(sv.z) + a4 + wts[4]); z[5] = lrelu(bfh(sv.z) + a5 + wts[5]);
        z[6] = lrelu(bfl(sv.w) + a6 + wts[6]); z[7] = lrelu(bfh(sv.w) + a7 + wts[7]);

        float svl = wts[88];
#pragma unroll
        for (int j = 0; j < HD; ++j) {
            float acc = wts[72 + j];
#pragma unroll
            for (int c = 0; c < HD; ++c) acc += z[c] * wts[8 + c * HD + j];
            svl += lrelu(acc) * wts[80 + j];
        }
        float pf = lrelu(svl);
        float2 wf = *(const float2*)(Wf2 + (size_t)nl * 2);
        acc0 = pf * wf.x;
        acc1 = pf * wf.y;
    }

#pragma unroll
    for (int off = 32; off > 0; off >>= 1) {
        acc0 += __shfl_down(acc0, off);
        acc1 += __shfl_down(acc1, off);
    }
    if (lane == 0) { red[wv * 2] = acc0; red[wv * 2 + 1] = acc1; }
    __syncthreads();

    if (tid == 0) {
        float y0 = 0.f, y1 = 0.f;
#pragma unroll
        for (int w = 0; w < 8; ++w) { y0 += red[w * 2]; y1 += red[w * 2 + 1]; }
        *(float2*)(bparts + (size_t)b * 2) = make_float2(y0, y1);
    }
}

// ---------------------------------------------------------------------------
// K4: finalize — one thread per graph sums 4 block partials, log_softmax.
// ---------------------------------------------------------------------------
__global__ __launch_bounds__(64) void k_fin(const float* __restrict__ bparts,
                                            const float* __restrict__ bf2,
                                            float* __restrict__ out, int Bn) {
    int g = threadIdx.x;
    if (g >= Bn) return;
    float y0 = bf2[0], y1 = bf2[1];
#pragma unroll
    for (int b = 0; b < 4; ++b) {
        float2 v = *(const float2*)(bparts + (size_t)(g * 4 + b) * 2);
        y0 += v.x; y1 += v.y;
    }
    float m = fmaxf(y0, y1);
    float lse = m + logf(expf(y0 - m) + expf(y1 - m));
    out[g * 2 + 0] = y0 - lse;
    out[g * 2 + 1] = y1 - lse;
}

// ---------------------------------------------------------------------------
extern "C" void kernel_launch(void* const* d_in, const int* in_sizes, int n_in,
                              void* d_out, int out_size, void* d_ws, size_t ws_size,
                              hipStream_t stream) {
    const float* x   = (const float*)d_in[0];
    const int*   ei  = (const int*)  d_in[1];
    const float* W1a = (const float*)d_in[3];
    const float* b1a = (const float*)d_in[4];
    const float* W1b = (const float*)d_in[5];
    const float* b1b = (const float*)d_in[6];
    const float* W2a = (const float*)d_in[7];
    const float* b2a = (const float*)d_in[8];
    const float* W2b = (const float*)d_in[9];
    const float* b2b = (const float*)d_in[10];
    const float* Wf1 = (const float*)d_in[11];
    const float* bf1 = (const float*)d_in[12];
    const float* Wf2 = (const float*)d_in[13];
    const float* bf2 = (const float*)d_in[14];

    int N   = in_sizes[0] / NF;        // 128000
    int E   = in_sizes[1] / 2;         // 2048000
    int Bn  = N / NPG;                 // 64 graphs
    int NC  = Bn * 4;                  // 256 chunks

    // workspace carve-up (16B-aligned sections)
    unsigned short* t1b   = (unsigned short*)d_ws;              // N*8 bf16  2.0 MB
    unsigned short* ubuf  = t1b + (size_t)N * HD;               // N*8 bf16  2.0 MB
    unsigned short* gcolb = ubuf + (size_t)N * HD;              // E ushort  4.1 MB
    int*            rpc   = (int*)(gcolb + (size_t)E);          // NC*(NPG+1) 2.0 MB
    float*          bparts= (float*)(rpc + (size_t)NC * (NPG + 1) + 16); // 256*2

    k_featsort<<<NC + N / FNPB, 1024, 0, stream>>>(x, W1a, ei, t1b, gcolb, rpc,
                                                   N, E, NC);
    k_l1 <<<NC, 512, 0, stream>>>(t1b, rpc, gcolb, ubuf, b1a, W1b, b1b, W2a);
    k_l2 <<<NC, 512, 0, stream>>>(ubuf, rpc, gcolb, b2a, W2b, b2b, Wf1, bf1,
                                  Wf2, bparts);
    k_fin<<<1, 64, 0, stream>>>(bparts, bf2, (float*)d_out, Bn);
}

// Round 16
// 153.387 us; speedup vs baseline: 1.2420x; 1.0063x over previous
//
#include <hip/hip_runtime.h>
#include <math.h>

#define NF 128
#define HD 8
#define NPG 2000          // nodes per graph
#define EPB 8000          // edges per sort chunk (4 chunks per graph)
#define LPB 8             // layer blocks per graph
#define LNPB 250          // nodes per layer block
#define FNPB 128          // nodes per feat block (1024 thr)
#define SLOPE 0.01f

__device__ __forceinline__ float lrelu(float v) {
    return v > 0.0f ? v : SLOPE * v;
}
// bf16 helpers: RNE pack, cheap unpack
__device__ __forceinline__ unsigned short f2bf(float f) {
    unsigned int u = __float_as_uint(f);
    return (unsigned short)((u + 0x7FFFu + ((u >> 16) & 1u)) >> 16);
}
__device__ __forceinline__ float bfl(unsigned int p) {
    return __uint_as_float(p << 16);
}
__device__ __forceinline__ float bfh(unsigned int p) {
    return __uint_as_float(p & 0xFFFF0000u);
}

// ---------------------------------------------------------------------------
// K1: fused [sort 0..255: single global pass (packed edges staged in LDS)] +
//          [feat 256..1255: 128 nodes, thread=(node,col), bf16 t1 store].
// ---------------------------------------------------------------------------
__global__ __launch_bounds__(1024) void k_featsort(
    const float* __restrict__ x, const float* __restrict__ W1a,
    const int* __restrict__ ei, unsigned short* __restrict__ t1b,
    unsigned short* __restrict__ gcolb, int* __restrict__ rpc,
    int N, int E, int NC)
{
    __shared__ union {
        struct { float tile[FNPB * 132]; float wl[NF * HD]; } f;  // 71.7 KB
        struct { int cnt[NPG]; unsigned int pck[EPB]; int srt[EPB];
                 int wtot[16]; int wpre[16]; } s;                 // 72.3 KB
    } sm;

    const int tid = threadIdx.x;

    if ((int)blockIdx.x < NC) {
        // ---------------- sort chunk b ----------------
        const int b = blockIdx.x;
        const int g = b >> 2;
        const int lane = tid & 63;
        const int wv = tid >> 6;
        const int nodeBase = g * NPG;
        const int e0 = b * EPB;

        for (int i = tid; i < NPG; i += 1024) sm.s.cnt[i] = 0;
        __syncthreads();

        // single global pass: count + stage packed (dl,src) to LDS
        for (int e = e0 + tid; e < e0 + EPB; e += 1024) {
            int src = ei[e] - nodeBase;               // < 2048
            int dl = ei[E + e] - nodeBase;            // < 2048
            sm.s.pck[e - e0] = ((unsigned int)dl << 11) | (unsigned int)src;
            atomicAdd(&sm.s.cnt[dl], 1);              // native ds_add_u32
        }
        __syncthreads();

        // block-wide exclusive scan; thread t owns pair (2t, 2t+1)
        int c0 = 0, c1 = 0;
        if (tid < 1000) { c0 = sm.s.cnt[2 * tid]; c1 = sm.s.cnt[2 * tid + 1]; }
        int s = c0 + c1;
        int isc = s;
#pragma unroll
        for (int d = 1; d < 64; d <<= 1) {
            int o = __shfl_up(isc, d);
            if (lane >= d) isc += o;
        }
        if (lane == 63) sm.s.wtot[wv] = isc;
        __syncthreads();
        if (wv == 0) {
            int v = (lane < 16) ? sm.s.wtot[lane] : 0;
            int iv = v;
#pragma unroll
            for (int d = 1; d < 16; d <<= 1) {
                int o = __shfl_up(iv, d);
                if (lane >= d) iv += o;
            }
            if (lane < 16) sm.s.wpre[lane] = iv - v;
        }
        __syncthreads();
        int excl = isc - s + sm.s.wpre[wv];

        int* rpb = rpc + (size_t)b * (NPG + 1);
        if (tid < 1000) {
            sm.s.cnt[2 * tid]     = excl;
            sm.s.cnt[2 * tid + 1] = excl + c0;
            rpb[2 * tid]     = excl;
            rpb[2 * tid + 1] = excl + c0;
        }
        if (tid == 0) rpb[NPG] = EPB;
        __syncthreads();

        // scatter pass: all-LDS (pck read -> rtn atomic -> srt write)
        for (int i = tid; i < EPB; i += 1024) {
            unsigned int p = sm.s.pck[i];
            int dl = (int)(p >> 11);
            int src = (int)(p & 2047u);
            int pos = atomicAdd(&sm.s.cnt[dl], 1);    // ds_add_rtn_u32
            sm.s.srt[pos] = src;
        }
        __syncthreads();

        // coalesced dump as ushort (pack 2 per uint)
        unsigned int* dst = (unsigned int*)(gcolb + (size_t)b * EPB);
        for (int i = tid; i < EPB / 2; i += 1024) {
            unsigned int lo = (unsigned int)sm.s.srt[2 * i] & 0xFFFFu;
            unsigned int hi = (unsigned int)sm.s.srt[2 * i + 1] << 16;
            dst[i] = lo | hi;
        }
    } else {
        // ---------------- feat block: 128 nodes ----------------
        const size_t base = (size_t)(blockIdx.x - NC) * FNPB;

        if (tid < 256) ((float4*)sm.f.wl)[tid] = ((const float4*)W1a)[tid];

        const float4* xg = (const float4*)(x + base * NF);
#pragma unroll
        for (int i = 0; i < 4; ++i) {
            int idx = tid + i * 1024;
            float4 v = xg[idx];
            int n = idx >> 5;
            int k4 = idx & 31;
            *(float4*)(sm.f.tile + n * 132 + k4 * 4) = v;
        }
        __syncthreads();

        const int n = tid >> 3;
        const int col = tid & 7;
        float acc = 0.0f;
        const float* row = sm.f.tile + n * 132;
#pragma unroll
        for (int k4 = 0; k4 < 32; ++k4) {
            float4 r = *(const float4*)(row + k4 * 4);
            int kb = k4 * 4 * HD + col;
            acc += r.x * sm.f.wl[kb];
            acc += r.y * sm.f.wl[kb + HD];
            acc += r.z * sm.f.wl[kb + 2 * HD];
            acc += r.w * sm.f.wl[kb + 3 * HD];
        }
        t1b[(base + n) * HD + col] = f2bf(acc);
    }
}

// ---------------------------------------------------------------------------
// Batched gather: 8 independent clamped col loads, then 8 predicated LDS
// gathers; rare tail for degree > 8.
// ---------------------------------------------------------------------------
#define GATHER_CHUNK(P)                                                       \
    {                                                                         \
        int b0 = rs[P], cnt = re[P] - b0;                                     \
        int sl[8];                                                            \
        _Pragma("unroll")                                                     \
        for (int j = 0; j < 8; ++j) {                                         \
            int idx = (j < cnt) ? (b0 + j) : 0;                               \
            sl[j] = colp[P][idx];                                             \
        }                                                                     \
        _Pragma("unroll")                                                     \
        for (int j = 0; j < 8; ++j) {                                         \
            float w = (j < cnt) ? 1.0f : 0.0f;                                \
            uint4 v = tbl[sl[j]];                                             \
            a0 += w * bfl(v.x); a1 += w * bfh(v.x);                           \
            a2 += w * bfl(v.y); a3 += w * bfh(v.y);                           \
            a4 += w * bfl(v.z); a5 += w * bfh(v.z);                           \
            a6 += w * bfl(v.w); a7 += w * bfh(v.w);                           \
        }                                                                     \
        for (int e2 = b0 + 8; e2 < b0 + cnt; ++e2) {                          \
            uint4 v = tbl[colp[P][e2]];                                       \
            a0 += bfl(v.x); a1 += bfh(v.x);                                   \
            a2 += bfl(v.y); a3 += bfh(v.y);                                   \
            a4 += bfl(v.z); a5 += bfh(v.z);                                   \
            a6 += bfl(v.w); a7 += bfh(v.w);                                   \
        }                                                                     \
    }

// ---------------------------------------------------------------------------
// K2: layer 1. 8 blocks/graph x 512 thr = 512 blocks (16 waves/CU; 32 KB
// table allows 2 blocks/CU). 2 threads/node: half h gathers chunks {2h,2h+1},
// shfl_xor(1) merges, half-0 runs MLP1 + u pack.
// ---------------------------------------------------------------------------
__global__ __launch_bounds__(512) void k_l1(
    const unsigned short* __restrict__ t1b, const int* __restrict__ rpc,
    const unsigned short* __restrict__ gcolb, unsigned short* __restrict__ ub,
    const float* __restrict__ b1a, const float* __restrict__ W1b,
    const float* __restrict__ b1b, const float* __restrict__ W2a)
{
    __shared__ uint4 tbl[NPG];        // 32 KB
    __shared__ float wts[144];        // b1a[8] W1b[64] b1b[8] W2a[64]

    const int b = blockIdx.x;
    const int g = b >> 3;
    const int q = b & 7;
    const int tid = threadIdx.x;

    if (tid < 144) {
        float v;
        if (tid < 8)       v = b1a[tid];
        else if (tid < 72) v = W1b[tid - 8];
        else if (tid < 80) v = b1b[tid - 72];
        else               v = W2a[tid - 80];
        wts[tid] = v;
    }

    const uint4* src4 = (const uint4*)(t1b + (size_t)g * NPG * HD);
#pragma unroll
    for (int i = 0; i < 4; ++i) {
        int idx = tid + i * 512;
        if (idx < NPG) tbl[idx] = src4[idx];
    }
    __syncthreads();

    if (tid < 2 * LNPB) {
        const int node = tid >> 1;            // 0..249
        const int half = tid & 1;
        const int nl = q * LNPB + node;
        int rs[2], re[2];
        const unsigned short* colp[2];
#pragma unroll
        for (int p = 0; p < 2; ++p) {
            int ch = half * 2 + p;
            const int* rpb = rpc + (size_t)((g << 2) + ch) * (NPG + 1);
            colp[p] = gcolb + (size_t)((g << 2) + ch) * EPB;
            rs[p] = rpb[nl]; re[p] = rpb[nl + 1];
        }
        float a0 = 0, a1 = 0, a2 = 0, a3 = 0, a4 = 0, a5 = 0, a6 = 0, a7 = 0;
        GATHER_CHUNK(0) GATHER_CHUNK(1)
        // merge halves (partner = tid^1, same node)
        a0 += __shfl_xor(a0, 1); a1 += __shfl_xor(a1, 1);
        a2 += __shfl_xor(a2, 1); a3 += __shfl_xor(a3, 1);
        a4 += __shfl_xor(a4, 1); a5 += __shfl_xor(a5, 1);
        a6 += __shfl_xor(a6, 1); a7 += __shfl_xor(a7, 1);

        if (half == 0) {
            uint4 sv = tbl[nl];                       // self feature
            float z[HD];
            z[0] = lrelu(bfl(sv.x) + a0 + wts[0]); z[1] = lrelu(bfh(sv.x) + a1 + wts[1]);
            z[2] = lrelu(bfl(sv.y) + a2 + wts[2]); z[3] = lrelu(bfh(sv.y) + a3 + wts[3]);
            z[4] = lrelu(bfl(sv.z) + a4 + wts[4]); z[5] = lrelu(bfh(sv.z) + a5 + wts[5]);
            z[6] = lrelu(bfl(sv.w) + a6 + wts[6]); z[7] = lrelu(bfh(sv.w) + a7 + wts[7]);

            float h[HD];
#pragma unroll
            for (int j = 0; j < HD; ++j) {
                float acc = wts[72 + j];
#pragma unroll
                for (int c = 0; c < HD; ++c) acc += z[c] * wts[8 + c * HD + j];
                h[j] = lrelu(acc);
            }
            float uu[HD];
#pragma unroll
            for (int j = 0; j < HD; ++j) {
                float acc = 0.0f;
#pragma unroll
                for (int c = 0; c < HD; ++c) acc += h[c] * wts[80 + c * HD + j];
                uu[j] = acc;
            }
            uint4 pk;
            pk.x = (unsigned int)f2bf(uu[0]) | ((unsigned int)f2bf(uu[1]) << 16);
            pk.y = (unsigned int)f2bf(uu[2]) | ((unsigned int)f2bf(uu[3]) << 16);
            pk.z = (unsigned int)f2bf(uu[4]) | ((unsigned int)f2bf(uu[5]) << 16);
            pk.w = (unsigned int)f2bf(uu[6]) | ((unsigned int)f2bf(uu[7]) << 16);
            ((uint4*)ub)[(size_t)g * NPG + nl] = pk;
        }
    }
}

// ---------------------------------------------------------------------------
// K3: layer 2, same 2-thr/node structure over ub; MLP2 + FC1 + FC2 partials;
// plain-store per-block partial (no device-scope sync — R6). k_fin finalizes.
// ---------------------------------------------------------------------------
__global__ __launch_bounds__(512) void k_l2(
    const unsigned short* __restrict__ ub, const int* __restrict__ rpc,
    const unsigned short* __restrict__ gcolb,
    const float* __restrict__ b2a, const float* __restrict__ W2b,
    const float* __restrict__ b2b, const float* __restrict__ Wf1,
    const float* __restrict__ bf1, const float* __restrict__ Wf2,
    float* __restrict__ bparts)
{
    __shared__ uint4 tbl[NPG];        // 32 KB
    __shared__ float wts[89];         // b2a[8] W2b[64] b2b[8] Wf1[8] bf1[1]
    __shared__ float red[16];

    const int b = blockIdx.x;
    const int g = b >> 3;
    const int q = b & 7;
    const int tid = threadIdx.x;
    const int lane = tid & 63;
    const int wv = tid >> 6;

    if (tid < 89) {
        float v;
        if (tid < 8)       v = b2a[tid];
        else if (tid < 72) v = W2b[tid - 8];
        else if (tid < 80) v = b2b[tid - 72];
        else if (tid < 88) v = Wf1[tid - 80];
        else               v = bf1[0];
        wts[tid] = v;
    }

    const uint4* src4 = (const uint4*)(ub + (size_t)g * NPG * HD);
#pragma unroll
    for (int i = 0; i < 4; ++i) {
        int idx = tid + i * 512;
        if (idx < NPG) tbl[idx] = src4[idx];
    }
    __syncthreads();

    float acc0 = 0.0f, acc1 = 0.0f;
    if (tid < 2 * LNPB) {
        const int node = tid >> 1;
        const int half = tid & 1;
        const int nl = q * LNPB + node;
        int rs[2], re[2];
        const unsigned short* colp[2];
#pragma unroll
        for (int p = 0; p < 2; ++p) {
            int ch = half * 2 + p;
            const int* rpb = rpc + (size_t)((g << 2) + ch) * (NPG + 1);
            colp[p] = gcolb + (size_t)((g << 2) + ch) * EPB;
            rs[p] = rpb[nl]; re[p] = rpb[nl + 1];
        }
        float a0 = 0, a1 = 0, a2 = 0, a3 = 0, a4 = 0, a5 = 0, a6 = 0, a7 = 0;
        GATHER_CHUNK(0) GATHER_CHUNK(1)
        a0 += __shfl_xor(a0, 1); a1 += __shfl_xor(a1, 1);
        a2 += __shfl_xor(a2, 1); a3 += __shfl_xor(a3, 1);
        a4 += __shfl_xor(a4, 1); a5 += __shfl_xor(a5, 1);
        a6 += __shfl_xor(a6, 1); a7 += __shfl_xor(a7, 1);

        if (half == 0) {
            uint4 sv = tbl[nl];
            float z[HD];
            z[0] = lrelu(bfl(sv.x) + a0 + wts[0]); z[1] = lrelu(bfh(sv.x) + a1 + wts[1]);
            z[2] = lrelu(bfl(sv.y) + a2 + wts[2]); z[3] = lrelu(bfh(sv.y) + a3 + wts[3]);
            z[4] = lrelu(bfl(sv.z) + a4 + wts[4]); z[5] = lrelu(bfh(sv.z) + a5 + wts[5]);
            z[6] = lrelu(bfl(sv.w) + a6 + wts[6]); z[7] = lrelu(bfh(sv.w) + a7 + wts[7]);

            float svl = wts[88];
#pragma unroll
            for (int j = 0; j < HD; ++j) {
                float acc = wts[72 + j];
#pragma unroll
                for (int c = 0; c < HD; ++c) acc += z[c] * wts[8 + c * HD + j];
                svl += lrelu(acc) * wts[80 + j];
            }
            float pf = lrelu(svl);
            float2 wf = *(const float2*)(Wf2 + (size_t)nl * 2);
            acc0 = pf * wf.x;
            acc1 = pf * wf.y;
        }
    }

#pragma unroll
    for (int off = 32; off > 0; off >>= 1) {
        acc0 += __shfl_down(acc0, off);
        acc1 += __shfl_down(acc1, off);
    }
    if (lane == 0) { red[wv * 2] = acc0; red[wv * 2 + 1] = acc1; }
    __syncthreads();

    if (tid == 0) {
        float y0 = 0.f, y1 = 0.f;
#pragma unroll
        for (int w = 0; w < 8; ++w) { y0 += red[w * 2]; y1 += red[w * 2 + 1]; }
        *(float2*)(bparts + (size_t)b * 2) = make_float2(y0, y1);
    }
}

// ---------------------------------------------------------------------------
// K4: finalize — one thread per graph sums 8 block partials, log_softmax.
// ---------------------------------------------------------------------------
__global__ __launch_bounds__(64) void k_fin(const float* __restrict__ bparts,
                                            const float* __restrict__ bf2,
                                            float* __restrict__ out, int Bn) {
    int g = threadIdx.x;
    if (g >= Bn) return;
    float y0 = bf2[0], y1 = bf2[1];
#pragma unroll
    for (int b = 0; b < LPB; ++b) {
        float2 v = *(const float2*)(bparts + (size_t)(g * LPB + b) * 2);
        y0 += v.x; y1 += v.y;
    }
    float m = fmaxf(y0, y1);
    float lse = m + logf(expf(y0 - m) + expf(y1 - m));
    out[g * 2 + 0] = y0 - lse;
    out[g * 2 + 1] = y1 - lse;
}

// ---------------------------------------------------------------------------
extern "C" void kernel_launch(void* const* d_in, const int* in_sizes, int n_in,
                              void* d_out, int out_size, void* d_ws, size_t ws_size,
                              hipStream_t stream) {
    const float* x   = (const float*)d_in[0];
    const int*   ei  = (const int*)  d_in[1];
    const float* W1a = (const float*)d_in[3];
    const float* b1a = (const float*)d_in[4];
    const float* W1b = (const float*)d_in[5];
    const float* b1b = (const float*)d_in[6];
    const float* W2a = (const float*)d_in[7];
    const float* b2a = (const float*)d_in[8];
    const float* W2b = (const float*)d_in[9];
    const float* b2b = (const float*)d_in[10];
    const float* Wf1 = (const float*)d_in[11];
    const float* bf1 = (const float*)d_in[12];
    const float* Wf2 = (const float*)d_in[13];
    const float* bf2 = (const float*)d_in[14];

    int N   = in_sizes[0] / NF;        // 128000
    int E   = in_sizes[1] / 2;         // 2048000
    int Bn  = N / NPG;                 // 64 graphs
    int NC  = Bn * 4;                  // 256 chunks

    // workspace carve-up (16B-aligned sections)
    unsigned short* t1b   = (unsigned short*)d_ws;              // N*8 bf16  2.0 MB
    unsigned short* ubuf  = t1b + (size_t)N * HD;               // N*8 bf16  2.0 MB
    unsigned short* gcolb = ubuf + (size_t)N * HD;              // E ushort  4.1 MB
    int*            rpc   = (int*)(gcolb + (size_t)E);          // NC*(NPG+1) 2.0 MB
    float*          bparts= (float*)(rpc + (size_t)NC * (NPG + 1) + 16); // 512*2

    k_featsort<<<NC + N / FNPB, 1024, 0, stream>>>(x, W1a, ei, t1b, gcolb, rpc,
                                                   N, E, NC);
    k_l1 <<<Bn * LPB, 512, 0, stream>>>(t1b, rpc, gcolb, ubuf, b1a, W1b, b1b, W2a);
    k_l2 <<<Bn * LPB, 512, 0, stream>>>(ubuf, rpc, gcolb, b2a, W2b, b2b, Wf1,
                                        bf1, Wf2, bparts);
    k_fin<<<1, 64, 0, stream>>>(bparts, bf2, (float*)d_out, Bn);
}